// Round 4
// baseline (246.605 us; speedup 1.0000x reference)
//
#include <hip/hip_runtime.h>
#include <hip/hip_fp16.h>
#include <math.h>

// 14-qubit batched statevector sim, MFMA engine. R14 = R13 (68.2 us kernel) +
// occupancy restructure. R13 post-mortem: latency-bound (no pipe >40%, 4
// waves/SIMD, occupancy 35%). R14 doubles resident waves by shrinking LDS:
//   - State lives in REGISTERS between passes (each wave's 4 A-frags = its
//     64x32 slab; 8 waves = the full 16K amplitudes). LDS is only the
//     exchange medium, so one 32 KB staging plane suffices: per pass
//     write-RE -> bar -> read-RE -> bar -> write-IM -> bar -> read-IM.
//     Same addresses/data as R13's reP/imP, just time-multiplexed by plane.
//   - LDS 66.2 KB -> 33.5 KB => 4 blocks/CU (LDS-wise); __launch_bounds__
//     (512,6) caps VGPR ~85 => >=24 waves/CU (vs 16). 4 barriers/pass
//     (vs 2) is cheap at this occupancy.
//
// Layouts kept from R7/R8/R11/R13 (verified):
//   staging (per plane): phys = t*512 + ((128*(k>>3) + 8*mlow + (k&7)) ^ swz(t))
//   gB planes octet-major: re at 256*(k>>3)+8*n+(k&7), im at +1024.
//   gC planes (A-frag order): UCr at 16*r+k, UCi at +256.
//   Superpass store: pS = (8q+2j+h)*512 + 128*(wave>>1)+4*(wave&1)
//                         + 8*(cc ^ (2j+h) ^ q), wrap CNOT(13,0) in v_perm sel.
// LDS: 32768 staging + 512 scratch + 192 angles = 33472 B.

#define NQ 14
#define NLAYERS 4
#define NCLASSES 10
#define BLOCK 512

typedef _Float16 f16;
typedef _Float16 f16x2 __attribute__((ext_vector_type(2)));
typedef _Float16 f16x4 __attribute__((ext_vector_type(4)));
typedef _Float16 f16x8 __attribute__((ext_vector_type(8)));
typedef float f32x4 __attribute__((ext_vector_type(4)));
typedef unsigned int u32;
typedef u32 u32x2 __attribute__((ext_vector_type(2)));

__device__ __forceinline__ f32x4 mf(f16x8 a, f16x8 b, f32x4 c) {
  return __builtin_amdgcn_mfma_f32_16x16x32_f16(a, b, c, 0, 0, 0);
}
__device__ __forceinline__ f32x4 mf16(f16x4 a, f16x4 b, f32x4 c) {
  return __builtin_amdgcn_mfma_f32_16x16x16f16(a, b, c, 0, 0, 0);
}
__device__ __forceinline__ int swz(int t) { return ((t ^ (t >> 3)) & 7) << 3; }

// packed f32x4 -> f16x4 (2x v_cvt_pkrtz_f16_f32)
__device__ __forceinline__ f16x4 cvt4(f32x4 v) {
  u32x2 r;
  r[0] = __builtin_bit_cast(u32, __builtin_amdgcn_cvt_pkrtz(v[0], v[1]));
  r[1] = __builtin_bit_cast(u32, __builtin_amdgcn_cvt_pkrtz(v[2], v[3]));
  return __builtin_bit_cast(f16x4, r);
}
__device__ __forceinline__ u32 dwof(f16x4 v, int k) {
  return __builtin_bit_cast(u32x2, v)[k];
}

__device__ __forceinline__ int finv5(int n) {
  n ^= ((n >> 3) & 1) << 4;
  n ^= ((n >> 2) & 1) << 3;
  n ^= ((n >> 1) & 1) << 2;
  n ^= (n & 1) << 1;
  return n;
}
__device__ __forceinline__ int finv3(int n) {
  n ^= ((n >> 2) & 1) << 3;
  n ^= ((n >> 1) & 1) << 2;
  n ^= (n & 1) << 1;
  return n;
}

// ---------------- pre-kernel: build all U planes once into workspace -------
// gB: 7 planes x 2048 f16 (re [0,1024), im [1024,2048)), pass order
//     {L1B, L2A, L2B, L3A, L3B, L4A, L4B}; plane p: layer l=(p+1)/2,
//     base = 14*l + (p odd ? 0 : 5).
// gC: 4 layers x 512 f16 (UCr at 16r+k, UCi at +256), base = 14*l + 10.
__global__ void qsim_build(const float* __restrict__ qp,
                           f16* __restrict__ gB, f16* __restrict__ gC) {
  __shared__ float qc[NLAYERS * NQ], qs[NLAYERS * NQ];
  const int tid = threadIdx.x;
  if (tid < NLAYERS * NQ) {
    float sv, cv; sincosf(0.5f * qp[tid], &sv, &cv);
    qc[tid] = cv; qs[tid] = sv;
  }
  __syncthreads();
#pragma unroll
  for (int p = 0; p < 7; ++p) {
    const int l = (p + 1) >> 1;
    const int base = 14 * l + ((p & 1) ? 0 : 5);
    const float c0 = qc[base], c1 = qc[base+1], c2 = qc[base+2], c3 = qc[base+3], c4 = qc[base+4];
    const float s0 = qs[base], s1 = qs[base+1], s2 = qs[base+2], s3 = qs[base+3], s4 = qs[base+4];
#pragma unroll
    for (int e = tid; e < 1024; e += BLOCK) {
      const int n = e >> 5, k = e & 31;
      const int d = finv5(n) ^ k;
      float mag = ((d & 1) ? s0 : c0) * ((d & 2) ? s1 : c1);
      mag *= ((d & 4) ? s2 : c2) * ((d & 8) ? s3 : c3);
      mag *= ((d & 16) ? s4 : c4);
      const int t = __popc(d) & 3;
      const f16 v = (f16)((t == 1 || t == 2) ? -mag : mag);
      const int pp = 256 * (k >> 3) + 8 * n + (k & 7);
      const bool isreal = !(t & 1);
      gB[p * 2048 + pp]        = isreal ? v : (f16)0.f;
      gB[p * 2048 + pp + 1024] = isreal ? (f16)0.f : v;
    }
  }
#pragma unroll
  for (int e = tid; e < 1024; e += BLOCK) {
    const int li = e >> 8, rp = (e >> 4) & 15, k = e & 15;
    const int base = 14 * li + 10;
    const float c0 = qc[base], c1 = qc[base+1], c2 = qc[base+2], c3 = qc[base+3];
    const float s0 = qs[base], s1 = qs[base+1], s2 = qs[base+2], s3 = qs[base+3];
    const int d = finv3(rp) ^ k;
    float mag = ((d & 1) ? s0 : c0) * ((d & 2) ? s1 : c1);
    mag *= ((d & 4) ? s2 : c2) * ((d & 8) ? s3 : c3);
    const int t = __popc(d) & 3;
    const f16 v = (f16)((t == 1 || t == 2) ? -mag : mag);
    const bool isreal = !(t & 1);
    const int pp = li * 512 + 16 * rp + k;
    gC[pp]       = isreal ? v : (f16)0.f;
    gC[pp + 256] = isreal ? (f16)0.f : v;
  }
}

// ---------------- per-wave fragment loaders (global, L1/L2-cached) ---------
struct FB { f16x8 br0, bi0, br1, bi1; };
struct FC { f16x4 ur0, ui0, ur1, ui1; };

__device__ __forceinline__ FB loadB(const f16* __restrict__ g, bool ctrl, int tid) {
  const int lane = tid & 63, wave = tid >> 6;
  const int q = lane >> 4, cc = lane & 15;
  int n0 = cc, n1 = cc | 16;
  if (ctrl && wave >= 4) { n0 ^= 31; n1 ^= 31; }   // ext-ctrl CNOT(4,5)
  FB f;
  f.br0 = *(const f16x8*)(g + 256 * q + 8 * n0);
  f.bi0 = *(const f16x8*)(g + 1024 + 256 * q + 8 * n0);
  f.br1 = *(const f16x8*)(g + 256 * q + 8 * n1);
  f.bi1 = *(const f16x8*)(g + 1024 + 256 * q + 8 * n1);
  return f;
}
__device__ __forceinline__ FC loadC(const f16* __restrict__ g, int tid) {
  const int lane = tid & 63;
  const int q = lane >> 4, cc = lane & 15;
  // both ext-ctrl(9,10) variants (ctrl = wire9 = half -> row^15)
  const int r0 = 16 * cc + 4 * q, r1 = 16 * (cc ^ 15) + 4 * q;
  FC f;
  f.ur0 = *(const f16x4*)(g + r0);
  f.ui0 = *(const f16x4*)(g + 256 + r0);
  f.ur1 = *(const f16x4*)(g + r1);
  f.ui1 = *(const f16x4*)(g + 256 + r1);
  return f;
}

// ---------------- exchange primitives (one 32 KB plane at a time) ----------
// A-frag read: identical pattern for every pass (R13's pA formula).
__device__ __forceinline__ void readFrag(const f16* __restrict__ stg, int tid,
                                         f16x8 A[4]) {
  const int lane = tid & 63, wave = tid >> 6;
  const int q = lane >> 4, cc = lane & 15;
#pragma unroll
  for (int i = 0; i < 4; ++i) {
    const int mt = wave * 4 + i;
    A[i] = *(const f16x8*)(stg + mt * 512 + ((128 * q + 8 * cc) ^ swz(mt)));
  }
}
// passA-store of one plane (R13's pS formula).
__device__ __forceinline__ void storeA(f16* __restrict__ stg, int tid,
                                       const f16x4 o[8]) {
  const int lane = tid & 63, wave = tid >> 6;
  const int q = lane >> 4, cc = lane & 15;
#pragma unroll
  for (int i = 0; i < 4; ++i) {
    const int mt = wave * 4 + i;
#pragma unroll
    for (int nt = 0; nt < 2; ++nt) {
      const int n5 = nt * 16 + cc;
      const int pS = n5 * 512 +
          ((128 * (2 * (mt & 1) + (q >> 1)) + 8 * (mt >> 1) + 4 * (q & 1)) ^ swz(n5));
      *(f16x4*)(stg + pS) = o[i * 2 + nt];
    }
  }
}
// superBC-store of one plane (v_perm pairing; wrap CNOT(13,0) in selector).
__device__ __forceinline__ void storeBC(f16* __restrict__ stg, int tid,
                                        const f16x4 a[4][2]) {
  const int lane = tid & 63, wave = tid >> 6;
  const int q = lane >> 4, cc = lane & 15;
  const u32 selLo = (q & 2) ? 0x01000504u : 0x05040100u;
  const u32 selHi = (q & 2) ? 0x03020706u : 0x07060302u;
  const int ibase = 128 * (wave >> 1) + 4 * (wave & 1);
#pragma unroll
  for (int h = 0; h < 2; ++h) {
#pragma unroll
    for (int j = 0; j < 4; ++j) {
      const int pS = (8 * q + 2 * j + h) * 512 + ibase + 8 * (cc ^ (2 * j + h) ^ q);
      const int dj = j >> 1;
      const u32 sel = (j & 1) ? selHi : selLo;
      u32x2 v;
      v[0] = __builtin_amdgcn_perm(dwof(a[1][h], dj), dwof(a[0][h], dj), sel);
      v[1] = __builtin_amdgcn_perm(dwof(a[3][h], dj), dwof(a[2][h], dj), sel);
      *(u32x2*)(stg + pS) = v;
    }
  }
}
__device__ __forceinline__ void exchangeA(f16* __restrict__ stg, int tid,
                                          const f16x4 oR[8], const f16x4 oI[8],
                                          f16x8 Ar[4], f16x8 Ai[4]) {
  __syncthreads();                 // prior reads of staging done
  storeA(stg, tid, oR);
  __syncthreads();
  readFrag(stg, tid, Ar);
  __syncthreads();                 // RE reads done before IM overwrite
  storeA(stg, tid, oI);
  __syncthreads();
  readFrag(stg, tid, Ai);
}
__device__ __forceinline__ void exchangeBC(f16* __restrict__ stg, int tid,
                                           const f16x4 aR[4][2], const f16x4 aI[4][2],
                                           f16x8 Ar[4], f16x8 Ai[4]) {
  __syncthreads();
  storeBC(stg, tid, aR);
  __syncthreads();
  readFrag(stg, tid, Ar);
  __syncthreads();
  storeBC(stg, tid, aI);
  __syncthreads();
  readFrag(stg, tid, Ai);
}

// ---------------- compute phases (pure register math) ----------------------
// A-pass (wires 0-4, no ext ctrl).
__device__ __forceinline__ void computeA(const f16x8 Ar[4], const f16x8 Ai[4],
                                         const FB& fb, f16x4 oR[8], f16x4 oI[8]) {
#pragma unroll
  for (int i = 0; i < 4; ++i) {
    const f16x8 nAi = -Ai[i];
    {
      f32x4 aR = {0.f,0.f,0.f,0.f}, aI = {0.f,0.f,0.f,0.f};
      aR = mf(Ar[i], fb.br0, aR); aR = mf(nAi, fb.bi0, aR);
      aI = mf(Ar[i], fb.bi0, aI); aI = mf(Ai[i], fb.br0, aI);
      oR[i * 2 + 0] = cvt4(aR);
      oI[i * 2 + 0] = cvt4(aI);
    }
    {
      f32x4 aR = {0.f,0.f,0.f,0.f}, aI = {0.f,0.f,0.f,0.f};
      aR = mf(Ar[i], fb.br1, aR); aR = mf(nAi, fb.bi1, aR);
      aI = mf(Ar[i], fb.bi1, aI); aI = mf(Ai[i], fb.br1, aI);
      oR[i * 2 + 1] = cvt4(aR);
      oI[i * 2 + 1] = cvt4(aI);
    }
  }
}

// Fused B+C superpass (R11-verified algebra). FINAL: fused readout.
template<bool FINAL>
__device__ __forceinline__ void computeBC(const f16x8 Ar[4], const f16x8 Ai[4],
                                          const FB& fb, const FC& fc,
                                          f16x4 aR4[4][2], f16x4 aI4[4][2],
                                          int tid, float* __restrict__ zloc) {
  const int lane = tid & 63, wave = tid >> 6;
  const int q = lane >> 4, cc = lane & 15;
  const f16x4 ucn0 = -fc.ui0, ucn1 = -fc.ui1;   // -UCi planes in-register
  float z0b = 0.f, z1b = 0.f, z9b = 0.f, zA = 0.f, zB = 0.f, pt = 0.f;
#pragma unroll
  for (int i = 0; i < 4; ++i) {
    const f16x8 nAi = -Ai[i];
#pragma unroll
    for (int h = 0; h < 2; ++h) {
      const f16x8 br = h ? fb.br1 : fb.br0;
      const f16x8 bi = h ? fb.bi1 : fb.bi0;
      f32x4 aR = {0.f,0.f,0.f,0.f}, aI = {0.f,0.f,0.f,0.f};
      aR = mf(Ar[i], br, aR); aR = mf(nAi, bi, aR);
      aI = mf(Ar[i], bi, aI); aI = mf(Ai[i], br, aI);
      const f16x4 s1r = cvt4(aR), s1i = cvt4(aI);
      const f16x4 ur = h ? fc.ur1 : fc.ur0;
      const f16x4 ui = h ? fc.ui1 : fc.ui0;
      const f16x4 un = h ? ucn1 : ucn0;
      f32x4 cR = {0.f,0.f,0.f,0.f}, cI = {0.f,0.f,0.f,0.f};
      cR = mf16(ur, s1r, cR); cR = mf16(un, s1i, cR);   // UCr*S1r - UCi*S1i
      cI = mf16(ui, s1r, cI); cI = mf16(ur, s1i, cI);   // UCi*S1r + UCr*S1i
      if constexpr (FINAL) {
        // element (wires): 0-1=i bits [+wrap], 2-4=wave bits, 5-8=cc bits,
        // 9=h, 10-11=j bits, 12-13=q bits; wrap: wire0 ^= (q>>1).
        const float p0 = cR[0]*cR[0] + cI[0]*cI[0];
        const float p1 = cR[1]*cR[1] + cI[1]*cI[1];
        const float p2 = cR[2]*cR[2] + cI[2]*cI[2];
        const float p3 = cR[3]*cR[3] + cI[3]*cI[3];
        const float ps = (p0 + p1) + (p2 + p3);
        zA += (p0 - p1) + (p2 - p3);          // Z10 (j bit0)
        zB += (p0 + p1) - (p2 + p3);          // Z11 (j bit1)
        z0b += (i & 1) ? -ps : ps;
        z1b += (i & 2) ? -ps : ps;
        z9b += h ? -ps : ps;
        pt  += ps;
      } else {
        aR4[i][h] = cvt4(cR);
        aI4[i][h] = cvt4(cI);
      }
    }
  }
  if constexpr (FINAL) {
    zloc[0]  += (q & 2) ? -z0b : z0b;   // wrap CNOT(13,0) sign fold
    zloc[1]  += z1b;
    zloc[2]  += (wave & 1) ? -pt : pt;
    zloc[3]  += (wave & 2) ? -pt : pt;
    zloc[4]  += (wave & 4) ? -pt : pt;
    zloc[5]  += (cc & 1) ? -pt : pt;
    zloc[6]  += (cc & 2) ? -pt : pt;
    zloc[7]  += (cc & 4) ? -pt : pt;
    zloc[8]  += (cc & 8) ? -pt : pt;
    zloc[9]  += z9b;
    zloc[10] += zA;
    zloc[11] += zB;
    zloc[12] += (q & 1) ? -pt : pt;
    zloc[13] += (q & 2) ? -pt : pt;
  }
}

__global__ __launch_bounds__(BLOCK, 6) void qsim_kernel(
    const float* __restrict__ x, const float* __restrict__ qp,
    const float* __restrict__ fcw, const float* __restrict__ fcb,
    const f16* __restrict__ gB, const f16* __restrict__ gC,
    float* __restrict__ out) {
  extern __shared__ unsigned char smem[];
  f16* stg = (f16*)smem;                    // [16384] one-plane staging
  float* scratch = (float*)(stg + 16384);   // [128] init scratch / zpart
  float* qc = scratch + 128;                // [8]  (only 0..4 used)
  float* qs = qc + 8;                       // [8]
  float* xc = qs + 8;                       // [16] (only 0..13 used)
  float* xs = xc + 16;                      // [16]

  const int b = blockIdx.x;
  const int tid = threadIdx.x;

  // L1-B / L1-C frags: issue global loads immediately (drain at init barriers)
  FB fb = loadB(gB, true, tid);
  FC fc = loadC(gC, tid);

  // ---- angles ----
  if (tid < NQ) {
    float sv, cv; sincosf(0.5f * x[b * NQ + tid], &sv, &cv);
    xc[tid] = cv; xs[tid] = sv;
  } else if (tid >= 64 && tid < 64 + 5) {
    const int k = tid - 64;
    float sv, cv; sincosf(0.5f * qp[k], &sv, &cv);
    qc[k] = cv; qs[k] = sv;
  }
  __syncthreads();

  // ---- closed-form state at L1-B entry ----
  float* Flo  = scratch;            // [32]
  float* psi  = Flo + 32;           // [32]
  float* PsiR = psi + 32;           // [32]
  float* PsiI = PsiR + 32;          // [32]
  if (tid < 32) {
    float f = 1.f;
#pragma unroll
    for (int j = 0; j < 5; ++j) f *= ((tid >> j) & 1) ? xs[5 + j] : xc[5 + j];
    Flo[tid] = f;
  } else if (tid < 64) {
    const int k = tid - 32;
    float f = 1.f;
#pragma unroll
    for (int j = 0; j < 5; ++j) f *= ((k >> j) & 1) ? xs[j] : xc[j];
    psi[k] = f;
  }
  __syncthreads();
  if (tid < 32) {   // Psi = U_L1A * psi
    const float c0 = qc[0], c1 = qc[1], c2 = qc[2], c3 = qc[3], c4 = qc[4];
    const float s0 = qs[0], s1 = qs[1], s2 = qs[2], s3 = qs[3], s4 = qs[4];
    const int a = finv5(tid);
    float ar = 0.f, ai = 0.f;
    for (int k = 0; k < 32; ++k) {
      const int d = a ^ k;
      float mag = ((d & 1) ? s0 : c0) * ((d & 2) ? s1 : c1);
      mag *= ((d & 4) ? s2 : c2) * ((d & 8) ? s3 : c3);
      mag *= ((d & 16) ? s4 : c4);
      mag *= psi[k];
      const int t = __popc(d) & 3;
      if (t == 0) ar += mag; else if (t == 1) ai -= mag;
      else if (t == 2) ar -= mag; else ai += mag;
    }
    PsiR[tid] = ar; PsiI[tid] = ai;
  }
  __syncthreads();

  // ---- init exchange: write RE plane, read RE frags; same for IM ----
  f16x8 Ar[4], Ai[4];
  {
    float fhi = 1.f;
#pragma unroll
    for (int j = 0; j < 4; ++j) fhi *= ((tid >> j) & 1) ? xs[10 + j] : xc[10 + j];
    const float cr = fhi * PsiR[tid >> 4], ci = fhi * PsiI[tid >> 4];
    const int t = tid >> 4;
    const int sz = swz(t);
#pragma unroll
    for (int kb = 0; kb < 4; ++kb) {
      f16x8 hr;
#pragma unroll
      for (int j = 0; j < 8; ++j) hr[j] = (f16)(Flo[8 * kb + j] * cr);
      *(f16x8*)(stg + t * 512 + ((128 * kb + 8 * (tid & 15)) ^ sz)) = hr;
    }
    __syncthreads();
    readFrag(stg, tid, Ar);
    __syncthreads();
#pragma unroll
    for (int kb = 0; kb < 4; ++kb) {
      f16x8 hi;
#pragma unroll
      for (int j = 0; j < 8; ++j) hi[j] = (f16)(Flo[8 * kb + j] * ci);
      *(f16x8*)(stg + t * 512 + ((128 * kb + 8 * (tid & 15)) ^ sz)) = hi;
    }
    __syncthreads();
    readFrag(stg, tid, Ai);
  }

  // ---- 7 passes; state in regs, staging exchange between passes ----
  // gB plane order {L1B, L2A, L2B, L3A, L3B, L4A, L4B}.
  f16x4 aR4[4][2], aI4[4][2];
  f16x4 oR[8], oI[8];
  FB fbA, fbB; FC fcB;

  fbA = loadB(gB + 1 * 2048, false, tid);                 // L2-A frags
  computeBC<false>(Ar, Ai, fb, fc, aR4, aI4, tid, nullptr);   // L1 B+C
  exchangeBC(stg, tid, aR4, aI4, Ar, Ai);

  fbB = loadB(gB + 2 * 2048, true, tid);                  // L2-B frags
  fcB = loadC(gC + 1 * 512, tid);
  computeA(Ar, Ai, fbA, oR, oI);                          // L2 A
  exchangeA(stg, tid, oR, oI, Ar, Ai);

  fbA = loadB(gB + 3 * 2048, false, tid);                 // L3-A frags
  computeBC<false>(Ar, Ai, fbB, fcB, aR4, aI4, tid, nullptr); // L2 B+C
  exchangeBC(stg, tid, aR4, aI4, Ar, Ai);

  fbB = loadB(gB + 4 * 2048, true, tid);                  // L3-B frags
  fcB = loadC(gC + 2 * 512, tid);
  computeA(Ar, Ai, fbA, oR, oI);                          // L3 A
  exchangeA(stg, tid, oR, oI, Ar, Ai);

  fbA = loadB(gB + 5 * 2048, false, tid);                 // L4-A frags
  computeBC<false>(Ar, Ai, fbB, fcB, aR4, aI4, tid, nullptr); // L3 B+C
  exchangeBC(stg, tid, aR4, aI4, Ar, Ai);

  fbB = loadB(gB + 6 * 2048, true, tid);                  // L4-B frags
  fcB = loadC(gC + 3 * 512, tid);
  computeA(Ar, Ai, fbA, oR, oI);                          // L4 A
  exchangeA(stg, tid, oR, oI, Ar, Ai);

  float zloc[NQ];
#pragma unroll
  for (int w = 0; w < NQ; ++w) zloc[w] = 0.f;
  computeBC<true>(Ar, Ai, fbB, fcB, aR4, aI4, tid, zloc);     // L4 B+C + readout
  __syncthreads();

  // ---- reduce + linear head (zpart aliases scratch) ----
  float* zpart = scratch;            // [8*14]
  float* zbuf  = zpart + 112;        // [14]
#pragma unroll
  for (int w = 0; w < NQ; ++w) {
#pragma unroll
    for (int off = 32; off > 0; off >>= 1)
      zloc[w] += __shfl_down(zloc[w], off, 64);
  }
  const int wave = tid >> 6, lane = tid & 63;
  if (lane == 0) {
#pragma unroll
    for (int w = 0; w < NQ; ++w) zpart[wave * NQ + w] = zloc[w];
  }
  __syncthreads();
  if (tid < NQ) {
    float a = 0.f;
#pragma unroll
    for (int v = 0; v < 8; ++v) a += zpart[v * NQ + tid];
    zbuf[tid] = a;
  }
  __syncthreads();
  if (tid < NCLASSES) {
    float acc = fcb[tid];
#pragma unroll
    for (int w = 0; w < NQ; ++w) acc = fmaf(zbuf[w], fcw[tid * NQ + w], acc);
    out[b * NCLASSES + tid] = acc;
  }
}

extern "C" void kernel_launch(void* const* d_in, const int* in_sizes, int n_in,
                              void* d_out, int out_size, void* d_ws, size_t ws_size,
                              hipStream_t stream) {
  const float* x   = (const float*)d_in[0];
  const float* qp  = (const float*)d_in[1];
  const float* fcw = (const float*)d_in[2];
  const float* fcb = (const float*)d_in[3];
  float* out = (float*)d_out;
  const int B = in_sizes[0] / NQ;

  f16* gB = (f16*)d_ws;              // 7 * 2048 f16 = 28672 B
  f16* gC = gB + 7 * 2048;           // 4 * 512 f16  =  4096 B (total 32 KB)

  qsim_build<<<1, BLOCK, 0, stream>>>(qp, gB, gC);

  const size_t shmem = (size_t)16384 * sizeof(f16)
                     + (size_t)(128 + 8 + 8 + 16 + 16) * sizeof(float);  // 33472 B
  (void)hipFuncSetAttribute((const void*)qsim_kernel,
                            hipFuncAttributeMaxDynamicSharedMemorySize, (int)shmem);
  qsim_kernel<<<B, BLOCK, shmem, stream>>>(x, qp, fcw, fcb, gB, gC, out);
}

// Round 6
// 219.986 us; speedup vs baseline: 1.1210x; 1.1210x over previous
//
#include <hip/hip_runtime.h>
#include <hip/hip_fp16.h>
#include <math.h>

// 14-qubit batched statevector sim, MFMA engine. R16 = R15 with the LDS
// aliasing UB removed. R15 post-mortem: tripwire caught run-to-run divergence
// (race). Cause: exchange helpers took the SAME staging pointer as
// `f16* __restrict__` (stores) and `const f16* __restrict__` (reads) —
// after inlining this asserts no-alias between the ds_writes and ds_reads of
// the same plane, letting the scheduler break the barrier-ordered exchange.
// Fix: NO __restrict__ on any LDS pointer (globals keep it). Structure,
// addresses, arithmetic byte-identical to R14/R15 (R14 verified correct):
//   - State in registers between passes; one 32 KB staging plane, exchange
//     per pass: [bar] store-RE [bar] read-RE [bar] store-IM [bar] read-IM.
//   - No cross-pass prefetch: fb/fc loaded right before their compute
//     (single FB/FC vars, minimal live set; R14's prefetch spilled at cap 84).
//   - __launch_bounds__(512,6): 3 blocks/CU (24 waves), VGPR cap ~84.
//
// Layouts kept from R7/R8/R11/R13 (verified):
//   staging (per plane): phys = t*512 + ((128*(k>>3) + 8*mlow + (k&7)) ^ swz(t))
//   gB planes octet-major: re at 256*(k>>3)+8*n+(k&7), im at +1024.
//   gC planes (A-frag order): UCr at 16*r+k, UCi at +256.
//   Superpass store: pS = (8q+2j+h)*512 + 128*(wave>>1)+4*(wave&1)
//                         + 8*(cc ^ (2j+h) ^ q), wrap CNOT(13,0) in v_perm sel.
// LDS: 32768 staging + 512 scratch + 192 angles = 33472 B.

#define NQ 14
#define NLAYERS 4
#define NCLASSES 10
#define BLOCK 512

typedef _Float16 f16;
typedef _Float16 f16x2 __attribute__((ext_vector_type(2)));
typedef _Float16 f16x4 __attribute__((ext_vector_type(4)));
typedef _Float16 f16x8 __attribute__((ext_vector_type(8)));
typedef float f32x4 __attribute__((ext_vector_type(4)));
typedef unsigned int u32;
typedef u32 u32x2 __attribute__((ext_vector_type(2)));

__device__ __forceinline__ f32x4 mf(f16x8 a, f16x8 b, f32x4 c) {
  return __builtin_amdgcn_mfma_f32_16x16x32_f16(a, b, c, 0, 0, 0);
}
__device__ __forceinline__ f32x4 mf16(f16x4 a, f16x4 b, f32x4 c) {
  return __builtin_amdgcn_mfma_f32_16x16x16f16(a, b, c, 0, 0, 0);
}
__device__ __forceinline__ int swz(int t) { return ((t ^ (t >> 3)) & 7) << 3; }

// packed f32x4 -> f16x4 (2x v_cvt_pkrtz_f16_f32)
__device__ __forceinline__ f16x4 cvt4(f32x4 v) {
  u32x2 r;
  r[0] = __builtin_bit_cast(u32, __builtin_amdgcn_cvt_pkrtz(v[0], v[1]));
  r[1] = __builtin_bit_cast(u32, __builtin_amdgcn_cvt_pkrtz(v[2], v[3]));
  return __builtin_bit_cast(f16x4, r);
}
__device__ __forceinline__ u32 dwof(f16x4 v, int k) {
  return __builtin_bit_cast(u32x2, v)[k];
}

__device__ __forceinline__ int finv5(int n) {
  n ^= ((n >> 3) & 1) << 4;
  n ^= ((n >> 2) & 1) << 3;
  n ^= ((n >> 1) & 1) << 2;
  n ^= (n & 1) << 1;
  return n;
}
__device__ __forceinline__ int finv3(int n) {
  n ^= ((n >> 2) & 1) << 3;
  n ^= ((n >> 1) & 1) << 2;
  n ^= (n & 1) << 1;
  return n;
}

// ---------------- pre-kernel: build all U planes once into workspace -------
// gB: 7 planes x 2048 f16 (re [0,1024), im [1024,2048)), pass order
//     {L1B, L2A, L2B, L3A, L3B, L4A, L4B}; plane p: layer l=(p+1)/2,
//     base = 14*l + (p odd ? 0 : 5).
// gC: 4 layers x 512 f16 (UCr at 16r+k, UCi at +256), base = 14*l + 10.
__global__ void qsim_build(const float* __restrict__ qp,
                           f16* __restrict__ gB, f16* __restrict__ gC) {
  __shared__ float qc[NLAYERS * NQ], qs[NLAYERS * NQ];
  const int tid = threadIdx.x;
  if (tid < NLAYERS * NQ) {
    float sv, cv; sincosf(0.5f * qp[tid], &sv, &cv);
    qc[tid] = cv; qs[tid] = sv;
  }
  __syncthreads();
#pragma unroll
  for (int p = 0; p < 7; ++p) {
    const int l = (p + 1) >> 1;
    const int base = 14 * l + ((p & 1) ? 0 : 5);
    const float c0 = qc[base], c1 = qc[base+1], c2 = qc[base+2], c3 = qc[base+3], c4 = qc[base+4];
    const float s0 = qs[base], s1 = qs[base+1], s2 = qs[base+2], s3 = qs[base+3], s4 = qs[base+4];
#pragma unroll
    for (int e = tid; e < 1024; e += BLOCK) {
      const int n = e >> 5, k = e & 31;
      const int d = finv5(n) ^ k;
      float mag = ((d & 1) ? s0 : c0) * ((d & 2) ? s1 : c1);
      mag *= ((d & 4) ? s2 : c2) * ((d & 8) ? s3 : c3);
      mag *= ((d & 16) ? s4 : c4);
      const int t = __popc(d) & 3;
      const f16 v = (f16)((t == 1 || t == 2) ? -mag : mag);
      const int pp = 256 * (k >> 3) + 8 * n + (k & 7);
      const bool isreal = !(t & 1);
      gB[p * 2048 + pp]        = isreal ? v : (f16)0.f;
      gB[p * 2048 + pp + 1024] = isreal ? (f16)0.f : v;
    }
  }
#pragma unroll
  for (int e = tid; e < 1024; e += BLOCK) {
    const int li = e >> 8, rp = (e >> 4) & 15, k = e & 15;
    const int base = 14 * li + 10;
    const float c0 = qc[base], c1 = qc[base+1], c2 = qc[base+2], c3 = qc[base+3];
    const float s0 = qs[base], s1 = qs[base+1], s2 = qs[base+2], s3 = qs[base+3];
    const int d = finv3(rp) ^ k;
    float mag = ((d & 1) ? s0 : c0) * ((d & 2) ? s1 : c1);
    mag *= ((d & 4) ? s2 : c2) * ((d & 8) ? s3 : c3);
    const int t = __popc(d) & 3;
    const f16 v = (f16)((t == 1 || t == 2) ? -mag : mag);
    const bool isreal = !(t & 1);
    const int pp = li * 512 + 16 * rp + k;
    gC[pp]       = isreal ? v : (f16)0.f;
    gC[pp + 256] = isreal ? (f16)0.f : v;
  }
}

// ---------------- per-wave fragment loaders (global, L1/L2-cached) ---------
struct FB { f16x8 br0, bi0, br1, bi1; };
struct FC { f16x4 ur0, ui0, ur1, ui1; };

__device__ __forceinline__ FB loadB(const f16* __restrict__ g, bool ctrl, int tid) {
  const int lane = tid & 63, wave = tid >> 6;
  const int q = lane >> 4, cc = lane & 15;
  int n0 = cc, n1 = cc | 16;
  if (ctrl && wave >= 4) { n0 ^= 31; n1 ^= 31; }   // ext-ctrl CNOT(4,5)
  FB f;
  f.br0 = *(const f16x8*)(g + 256 * q + 8 * n0);
  f.bi0 = *(const f16x8*)(g + 1024 + 256 * q + 8 * n0);
  f.br1 = *(const f16x8*)(g + 256 * q + 8 * n1);
  f.bi1 = *(const f16x8*)(g + 1024 + 256 * q + 8 * n1);
  return f;
}
__device__ __forceinline__ FC loadC(const f16* __restrict__ g, int tid) {
  const int lane = tid & 63;
  const int q = lane >> 4, cc = lane & 15;
  // both ext-ctrl(9,10) variants (ctrl = wire9 = half -> row^15)
  const int r0 = 16 * cc + 4 * q, r1 = 16 * (cc ^ 15) + 4 * q;
  FC f;
  f.ur0 = *(const f16x4*)(g + r0);
  f.ui0 = *(const f16x4*)(g + 256 + r0);
  f.ur1 = *(const f16x4*)(g + r1);
  f.ui1 = *(const f16x4*)(g + 256 + r1);
  return f;
}

// ---------------- exchange primitives (one 32 KB plane at a time) ----------
// NOTE: NO __restrict__ on LDS pointers — store side and read side alias the
// same plane by design; barriers provide the ordering (R15 bug).
__device__ __forceinline__ void readFrag(const f16* stg, int tid, f16x8 A[4]) {
  const int lane = tid & 63, wave = tid >> 6;
  const int q = lane >> 4, cc = lane & 15;
#pragma unroll
  for (int i = 0; i < 4; ++i) {
    const int mt = wave * 4 + i;
    A[i] = *(const f16x8*)(stg + mt * 512 + ((128 * q + 8 * cc) ^ swz(mt)));
  }
}
// passA-store of one plane (R13's pS formula).
__device__ __forceinline__ void storeA(f16* stg, int tid, const f16x4 o[8]) {
  const int lane = tid & 63, wave = tid >> 6;
  const int q = lane >> 4, cc = lane & 15;
#pragma unroll
  for (int i = 0; i < 4; ++i) {
    const int mt = wave * 4 + i;
#pragma unroll
    for (int nt = 0; nt < 2; ++nt) {
      const int n5 = nt * 16 + cc;
      const int pS = n5 * 512 +
          ((128 * (2 * (mt & 1) + (q >> 1)) + 8 * (mt >> 1) + 4 * (q & 1)) ^ swz(n5));
      *(f16x4*)(stg + pS) = o[i * 2 + nt];
    }
  }
}
// superBC-store of one plane (v_perm pairing; wrap CNOT(13,0) in selector).
__device__ __forceinline__ void storeBC(f16* stg, int tid, const f16x4 a[4][2]) {
  const int lane = tid & 63, wave = tid >> 6;
  const int q = lane >> 4, cc = lane & 15;
  const u32 selLo = (q & 2) ? 0x01000504u : 0x05040100u;
  const u32 selHi = (q & 2) ? 0x03020706u : 0x07060302u;
  const int ibase = 128 * (wave >> 1) + 4 * (wave & 1);
#pragma unroll
  for (int h = 0; h < 2; ++h) {
#pragma unroll
    for (int j = 0; j < 4; ++j) {
      const int pS = (8 * q + 2 * j + h) * 512 + ibase + 8 * (cc ^ (2 * j + h) ^ q);
      const int dj = j >> 1;
      const u32 sel = (j & 1) ? selHi : selLo;
      u32x2 v;
      v[0] = __builtin_amdgcn_perm(dwof(a[1][h], dj), dwof(a[0][h], dj), sel);
      v[1] = __builtin_amdgcn_perm(dwof(a[3][h], dj), dwof(a[2][h], dj), sel);
      *(u32x2*)(stg + pS) = v;
    }
  }
}
__device__ __forceinline__ void exchangeA(f16* stg, int tid,
                                          const f16x4 oR[8], const f16x4 oI[8],
                                          f16x8 Ar[4], f16x8 Ai[4]) {
  __syncthreads();                 // prior reads of staging done
  storeA(stg, tid, oR);
  __syncthreads();
  readFrag(stg, tid, Ar);
  __syncthreads();                 // RE reads done before IM overwrite
  storeA(stg, tid, oI);
  __syncthreads();
  readFrag(stg, tid, Ai);
}
__device__ __forceinline__ void exchangeBC(f16* stg, int tid,
                                           const f16x4 aR[4][2], const f16x4 aI[4][2],
                                           f16x8 Ar[4], f16x8 Ai[4]) {
  __syncthreads();
  storeBC(stg, tid, aR);
  __syncthreads();
  readFrag(stg, tid, Ar);
  __syncthreads();
  storeBC(stg, tid, aI);
  __syncthreads();
  readFrag(stg, tid, Ai);
}

// ---------------- compute phases (pure register math) ----------------------
// A-pass (wires 0-4, no ext ctrl).
__device__ __forceinline__ void computeA(const f16x8 Ar[4], const f16x8 Ai[4],
                                         const FB& fb, f16x4 oR[8], f16x4 oI[8]) {
#pragma unroll
  for (int i = 0; i < 4; ++i) {
    const f16x8 nAi = -Ai[i];
    {
      f32x4 aR = {0.f,0.f,0.f,0.f}, aI = {0.f,0.f,0.f,0.f};
      aR = mf(Ar[i], fb.br0, aR); aR = mf(nAi, fb.bi0, aR);
      aI = mf(Ar[i], fb.bi0, aI); aI = mf(Ai[i], fb.br0, aI);
      oR[i * 2 + 0] = cvt4(aR);
      oI[i * 2 + 0] = cvt4(aI);
    }
    {
      f32x4 aR = {0.f,0.f,0.f,0.f}, aI = {0.f,0.f,0.f,0.f};
      aR = mf(Ar[i], fb.br1, aR); aR = mf(nAi, fb.bi1, aR);
      aI = mf(Ar[i], fb.bi1, aI); aI = mf(Ai[i], fb.br1, aI);
      oR[i * 2 + 1] = cvt4(aR);
      oI[i * 2 + 1] = cvt4(aI);
    }
  }
}

// Fused B+C superpass (R11-verified algebra). FINAL: fused readout.
template<bool FINAL>
__device__ __forceinline__ void computeBC(const f16x8 Ar[4], const f16x8 Ai[4],
                                          const FB& fb, const FC& fc,
                                          f16x4 aR4[4][2], f16x4 aI4[4][2],
                                          int tid, float* zloc) {
  const int lane = tid & 63, wave = tid >> 6;
  const int q = lane >> 4, cc = lane & 15;
  float z0b = 0.f, z1b = 0.f, z9b = 0.f, zA = 0.f, zB = 0.f, pt = 0.f;
#pragma unroll
  for (int i = 0; i < 4; ++i) {
    const f16x8 nAi = -Ai[i];
#pragma unroll
    for (int h = 0; h < 2; ++h) {
      const f16x8 br = h ? fb.br1 : fb.br0;
      const f16x8 bi = h ? fb.bi1 : fb.bi0;
      f32x4 aR = {0.f,0.f,0.f,0.f}, aI = {0.f,0.f,0.f,0.f};
      aR = mf(Ar[i], br, aR); aR = mf(nAi, bi, aR);
      aI = mf(Ar[i], bi, aI); aI = mf(Ai[i], br, aI);
      const f16x4 s1r = cvt4(aR), s1i = cvt4(aI);
      const f16x4 ur = h ? fc.ur1 : fc.ur0;
      const f16x4 ui = h ? fc.ui1 : fc.ui0;
      const f16x4 un = -ui;                           // transient -UCi
      f32x4 cR = {0.f,0.f,0.f,0.f}, cI = {0.f,0.f,0.f,0.f};
      cR = mf16(ur, s1r, cR); cR = mf16(un, s1i, cR);   // UCr*S1r - UCi*S1i
      cI = mf16(ui, s1r, cI); cI = mf16(ur, s1i, cI);   // UCi*S1r + UCr*S1i
      if constexpr (FINAL) {
        // element (wires): 0-1=i bits [+wrap], 2-4=wave bits, 5-8=cc bits,
        // 9=h, 10-11=j bits, 12-13=q bits; wrap: wire0 ^= (q>>1).
        const float p0 = cR[0]*cR[0] + cI[0]*cI[0];
        const float p1 = cR[1]*cR[1] + cI[1]*cI[1];
        const float p2 = cR[2]*cR[2] + cI[2]*cI[2];
        const float p3 = cR[3]*cR[3] + cI[3]*cI[3];
        const float ps = (p0 + p1) + (p2 + p3);
        zA += (p0 - p1) + (p2 - p3);          // Z10 (j bit0)
        zB += (p0 + p1) - (p2 + p3);          // Z11 (j bit1)
        z0b += (i & 1) ? -ps : ps;
        z1b += (i & 2) ? -ps : ps;
        z9b += h ? -ps : ps;
        pt  += ps;
      } else {
        aR4[i][h] = cvt4(cR);
        aI4[i][h] = cvt4(cI);
      }
    }
  }
  if constexpr (FINAL) {
    zloc[0]  += (q & 2) ? -z0b : z0b;   // wrap CNOT(13,0) sign fold
    zloc[1]  += z1b;
    zloc[2]  += (wave & 1) ? -pt : pt;
    zloc[3]  += (wave & 2) ? -pt : pt;
    zloc[4]  += (wave & 4) ? -pt : pt;
    zloc[5]  += (cc & 1) ? -pt : pt;
    zloc[6]  += (cc & 2) ? -pt : pt;
    zloc[7]  += (cc & 4) ? -pt : pt;
    zloc[8]  += (cc & 8) ? -pt : pt;
    zloc[9]  += z9b;
    zloc[10] += zA;
    zloc[11] += zB;
    zloc[12] += (q & 1) ? -pt : pt;
    zloc[13] += (q & 2) ? -pt : pt;
  }
}

__global__ __launch_bounds__(BLOCK, 6) void qsim_kernel(
    const float* __restrict__ x, const float* __restrict__ qp,
    const float* __restrict__ fcw, const float* __restrict__ fcb,
    const f16* __restrict__ gB, const f16* __restrict__ gC,
    float* __restrict__ out) {
  extern __shared__ unsigned char smem[];
  f16* stg = (f16*)smem;                    // [16384] one-plane staging
  float* scratch = (float*)(stg + 16384);   // [128] init scratch / zpart
  float* qc = scratch + 128;                // [8]  (only 0..4 used)
  float* qs = qc + 8;                       // [8]
  float* xc = qs + 8;                       // [16] (only 0..13 used)
  float* xs = xc + 16;                      // [16]

  const int b = blockIdx.x;
  const int tid = threadIdx.x;

  // ---- angles ----
  if (tid < NQ) {
    float sv, cv; sincosf(0.5f * x[b * NQ + tid], &sv, &cv);
    xc[tid] = cv; xs[tid] = sv;
  } else if (tid >= 64 && tid < 64 + 5) {
    const int k = tid - 64;
    float sv, cv; sincosf(0.5f * qp[k], &sv, &cv);
    qc[k] = cv; qs[k] = sv;
  }
  __syncthreads();

  // ---- closed-form state at L1-B entry ----
  float* Flo  = scratch;            // [32]
  float* psi  = Flo + 32;           // [32]
  float* PsiR = psi + 32;           // [32]
  float* PsiI = PsiR + 32;          // [32]
  if (tid < 32) {
    float f = 1.f;
#pragma unroll
    for (int j = 0; j < 5; ++j) f *= ((tid >> j) & 1) ? xs[5 + j] : xc[5 + j];
    Flo[tid] = f;
  } else if (tid < 64) {
    const int k = tid - 32;
    float f = 1.f;
#pragma unroll
    for (int j = 0; j < 5; ++j) f *= ((k >> j) & 1) ? xs[j] : xc[j];
    psi[k] = f;
  }
  __syncthreads();
  if (tid < 32) {   // Psi = U_L1A * psi
    const float c0 = qc[0], c1 = qc[1], c2 = qc[2], c3 = qc[3], c4 = qc[4];
    const float s0 = qs[0], s1 = qs[1], s2 = qs[2], s3 = qs[3], s4 = qs[4];
    const int a = finv5(tid);
    float ar = 0.f, ai = 0.f;
    for (int k = 0; k < 32; ++k) {
      const int d = a ^ k;
      float mag = ((d & 1) ? s0 : c0) * ((d & 2) ? s1 : c1);
      mag *= ((d & 4) ? s2 : c2) * ((d & 8) ? s3 : c3);
      mag *= ((d & 16) ? s4 : c4);
      mag *= psi[k];
      const int t = __popc(d) & 3;
      if (t == 0) ar += mag; else if (t == 1) ai -= mag;
      else if (t == 2) ar -= mag; else ai += mag;
    }
    PsiR[tid] = ar; PsiI[tid] = ai;
  }
  __syncthreads();

  // ---- init exchange: write RE plane, read RE frags; same for IM ----
  f16x8 Ar[4], Ai[4];
  {
    float fhi = 1.f;
#pragma unroll
    for (int j = 0; j < 4; ++j) fhi *= ((tid >> j) & 1) ? xs[10 + j] : xc[10 + j];
    const float cr = fhi * PsiR[tid >> 4], ci = fhi * PsiI[tid >> 4];
    const int t = tid >> 4;
    const int sz = swz(t);
#pragma unroll
    for (int kb = 0; kb < 4; ++kb) {
      f16x8 hr;
#pragma unroll
      for (int j = 0; j < 8; ++j) hr[j] = (f16)(Flo[8 * kb + j] * cr);
      *(f16x8*)(stg + t * 512 + ((128 * kb + 8 * (tid & 15)) ^ sz)) = hr;
    }
    __syncthreads();
    readFrag(stg, tid, Ar);
    __syncthreads();
#pragma unroll
    for (int kb = 0; kb < 4; ++kb) {
      f16x8 hi;
#pragma unroll
      for (int j = 0; j < 8; ++j) hi[j] = (f16)(Flo[8 * kb + j] * ci);
      *(f16x8*)(stg + t * 512 + ((128 * kb + 8 * (tid & 15)) ^ sz)) = hi;
    }
    __syncthreads();
    readFrag(stg, tid, Ai);
  }

  // ---- 7 passes; state in regs, staging exchange between passes ----
  // gB plane order {L1B, L2A, L2B, L3A, L3B, L4A, L4B}. fb/fc loaded just
  // before use (no cross-exchange prefetch -> minimal live set).
  f16x4 aR4[4][2], aI4[4][2];
  f16x4 oR[8], oI[8];

  FB fb = loadB(gB, true, tid);                               // L1-B
  FC fc = loadC(gC, tid);
  computeBC<false>(Ar, Ai, fb, fc, aR4, aI4, tid, nullptr);   // L1 B+C
  exchangeBC(stg, tid, aR4, aI4, Ar, Ai);

  fb = loadB(gB + 1 * 2048, false, tid);                      // L2-A
  computeA(Ar, Ai, fb, oR, oI);
  exchangeA(stg, tid, oR, oI, Ar, Ai);

  fb = loadB(gB + 2 * 2048, true, tid);                       // L2-B
  fc = loadC(gC + 1 * 512, tid);
  computeBC<false>(Ar, Ai, fb, fc, aR4, aI4, tid, nullptr);
  exchangeBC(stg, tid, aR4, aI4, Ar, Ai);

  fb = loadB(gB + 3 * 2048, false, tid);                      // L3-A
  computeA(Ar, Ai, fb, oR, oI);
  exchangeA(stg, tid, oR, oI, Ar, Ai);

  fb = loadB(gB + 4 * 2048, true, tid);                       // L3-B
  fc = loadC(gC + 2 * 512, tid);
  computeBC<false>(Ar, Ai, fb, fc, aR4, aI4, tid, nullptr);
  exchangeBC(stg, tid, aR4, aI4, Ar, Ai);

  fb = loadB(gB + 5 * 2048, false, tid);                      // L4-A
  computeA(Ar, Ai, fb, oR, oI);
  exchangeA(stg, tid, oR, oI, Ar, Ai);

  fb = loadB(gB + 6 * 2048, true, tid);                       // L4-B
  fc = loadC(gC + 3 * 512, tid);
  float zloc[NQ];
#pragma unroll
  for (int w = 0; w < NQ; ++w) zloc[w] = 0.f;
  computeBC<true>(Ar, Ai, fb, fc, aR4, aI4, tid, zloc);       // L4 B+C + readout
  __syncthreads();

  // ---- reduce + linear head (zpart aliases scratch) ----
  float* zpart = scratch;            // [8*14]
  float* zbuf  = zpart + 112;        // [14]
#pragma unroll
  for (int w = 0; w < NQ; ++w) {
#pragma unroll
    for (int off = 32; off > 0; off >>= 1)
      zloc[w] += __shfl_down(zloc[w], off, 64);
  }
  const int wave = tid >> 6, lane = tid & 63;
  if (lane == 0) {
#pragma unroll
    for (int w = 0; w < NQ; ++w) zpart[wave * NQ + w] = zloc[w];
  }
  __syncthreads();
  if (tid < NQ) {
    float a = 0.f;
#pragma unroll
    for (int v = 0; v < 8; ++v) a += zpart[v * NQ + tid];
    zbuf[tid] = a;
  }
  __syncthreads();
  if (tid < NCLASSES) {
    float acc = fcb[tid];
#pragma unroll
    for (int w = 0; w < NQ; ++w) acc = fmaf(zbuf[w], fcw[tid * NQ + w], acc);
    out[b * NCLASSES + tid] = acc;
  }
}

extern "C" void kernel_launch(void* const* d_in, const int* in_sizes, int n_in,
                              void* d_out, int out_size, void* d_ws, size_t ws_size,
                              hipStream_t stream) {
  const float* x   = (const float*)d_in[0];
  const float* qp  = (const float*)d_in[1];
  const float* fcw = (const float*)d_in[2];
  const float* fcb = (const float*)d_in[3];
  float* out = (float*)d_out;
  const int B = in_sizes[0] / NQ;

  f16* gB = (f16*)d_ws;              // 7 * 2048 f16 = 28672 B
  f16* gC = gB + 7 * 2048;           // 4 * 512 f16  =  4096 B (total 32 KB)

  qsim_build<<<1, BLOCK, 0, stream>>>(qp, gB, gC);

  const size_t shmem = (size_t)16384 * sizeof(f16)
                     + (size_t)(128 + 8 + 8 + 16 + 16) * sizeof(float);  // 33472 B
  (void)hipFuncSetAttribute((const void*)qsim_kernel,
                            hipFuncAttributeMaxDynamicSharedMemorySize, (int)shmem);
  qsim_kernel<<<B, BLOCK, shmem, stream>>>(x, qp, fcw, fcb, gB, gC, out);
}

// Round 8
// 198.281 us; speedup vs baseline: 1.2437x; 1.1095x over previous
//
#include <hip/hip_runtime.h>
#include <hip/hip_fp16.h>
#include <math.h>

// 14-qubit batched statevector sim, MFMA engine. R18 = R17 (slot-union
// register-state, 3 blocks/CU — failed absmax 1.263e-2 vs 1.1875e-2, a 6%
// overage in the f16-rounding-dominated regime) with all f32->f16
// conversions switched RTZ -> RNE:
//   - cvt4 now uses (f16) casts (v_cvt_f16_f32 RNE + v_pack_b32_f16) instead
//     of v_cvt_pkrtz (RTZ, 1-ulp biased). Unbiased rounding ~halves the
//     accumulated state error over 7 passes. Cost ~+700 VALU/thread.
//   - Everything else byte-identical to R17: state = u32 stR[16]/stI[16]
//     slot-union (peak ~76 VGPR, fits (512,6) cap -> 3 blocks/CU, 24 waves);
//     one 32 KB staging plane, exchange [bar] store-RE [bar] read-RE [bar]
//     store-IM [bar] read-IM; 6-acc FINAL readout; no __restrict__ on LDS
//     pointers (R15 race lesson).
// Experiment design: PASS => R17's failure was RTZ rounding sensitivity.
// FAIL again => real bug in the union; revert to R13 next round.
//
// Layouts kept from R7/R8/R11/R13 (verified):
//   staging (per plane): phys = t*512 + ((128*(k>>3) + 8*mlow + (k&7)) ^ swz(t))
//   gB planes octet-major: re at 256*(k>>3)+8*n+(k&7), im at +1024.
//   gC planes (A-frag order): UCr at 16*r+k, UCi at +256.
//   Superpass store: pS = (8q+2j+h)*512 + 128*(wave>>1)+4*(wave&1)
//                         + 8*(cc ^ (2j+h) ^ q), wrap CNOT(13,0) in v_perm sel.
// LDS: 32768 staging + 512 scratch + 192 angles = 33472 B.

#define NQ 14
#define NLAYERS 4
#define NCLASSES 10
#define BLOCK 512

typedef _Float16 f16;
typedef _Float16 f16x4 __attribute__((ext_vector_type(4)));
typedef _Float16 f16x8 __attribute__((ext_vector_type(8)));
typedef float f32x4 __attribute__((ext_vector_type(4)));
typedef unsigned int u32;
typedef u32 u32x2 __attribute__((ext_vector_type(2)));
typedef u32 u32x4 __attribute__((ext_vector_type(4)));

__device__ __forceinline__ f32x4 mf(f16x8 a, f16x8 b, f32x4 c) {
  return __builtin_amdgcn_mfma_f32_16x16x32_f16(a, b, c, 0, 0, 0);
}
__device__ __forceinline__ f32x4 mf16(f16x4 a, f16x4 b, f32x4 c) {
  return __builtin_amdgcn_mfma_f32_16x16x16f16(a, b, c, 0, 0, 0);
}
__device__ __forceinline__ int swz(int t) { return ((t ^ (t >> 3)) & 7) << 3; }

// f32x4 -> f16x4, ROUND-TO-NEAREST-EVEN (R18: was v_cvt_pkrtz = RTZ).
// Compiles to 4x v_cvt_f16_f32 + 2x v_pack_b32_f16.
__device__ __forceinline__ f16x4 cvt4(f32x4 v) {
  f16x4 r;
  r[0] = (f16)v[0]; r[1] = (f16)v[1]; r[2] = (f16)v[2]; r[3] = (f16)v[3];
  return r;
}

// state-slot helpers (all indices compile-time constant in unrolled loops)
__device__ __forceinline__ f16x8 ld8(const u32 st[16], int i) {
  u32x4 v = { st[4 * i], st[4 * i + 1], st[4 * i + 2], st[4 * i + 3] };
  return __builtin_bit_cast(f16x8, v);
}
__device__ __forceinline__ void st4(u32 st[16], int idx, f16x4 v) {
  const u32x2 d = __builtin_bit_cast(u32x2, v);
  st[idx] = d[0]; st[idx + 1] = d[1];
}

__device__ __forceinline__ int finv5(int n) {
  n ^= ((n >> 3) & 1) << 4;
  n ^= ((n >> 2) & 1) << 3;
  n ^= ((n >> 1) & 1) << 2;
  n ^= (n & 1) << 1;
  return n;
}
__device__ __forceinline__ int finv3(int n) {
  n ^= ((n >> 2) & 1) << 3;
  n ^= ((n >> 1) & 1) << 2;
  n ^= (n & 1) << 1;
  return n;
}

// ---------------- pre-kernel: build all U planes once into workspace -------
// gB: 7 planes x 2048 f16 (re [0,1024), im [1024,2048)), pass order
//     {L1B, L2A, L2B, L3A, L3B, L4A, L4B}.
// gC: 4 layers x 512 f16 (UCr at 16r+k, UCi at +256), base = 14*l + 10.
__global__ void qsim_build(const float* __restrict__ qp,
                           f16* __restrict__ gB, f16* __restrict__ gC) {
  __shared__ float qc[NLAYERS * NQ], qs[NLAYERS * NQ];
  const int tid = threadIdx.x;
  if (tid < NLAYERS * NQ) {
    float sv, cv; sincosf(0.5f * qp[tid], &sv, &cv);
    qc[tid] = cv; qs[tid] = sv;
  }
  __syncthreads();
#pragma unroll
  for (int p = 0; p < 7; ++p) {
    const int l = (p + 1) >> 1;
    const int base = 14 * l + ((p & 1) ? 0 : 5);
    const float c0 = qc[base], c1 = qc[base+1], c2 = qc[base+2], c3 = qc[base+3], c4 = qc[base+4];
    const float s0 = qs[base], s1 = qs[base+1], s2 = qs[base+2], s3 = qs[base+3], s4 = qs[base+4];
#pragma unroll
    for (int e = tid; e < 1024; e += BLOCK) {
      const int n = e >> 5, k = e & 31;
      const int d = finv5(n) ^ k;
      float mag = ((d & 1) ? s0 : c0) * ((d & 2) ? s1 : c1);
      mag *= ((d & 4) ? s2 : c2) * ((d & 8) ? s3 : c3);
      mag *= ((d & 16) ? s4 : c4);
      const int t = __popc(d) & 3;
      const f16 v = (f16)((t == 1 || t == 2) ? -mag : mag);
      const int pp = 256 * (k >> 3) + 8 * n + (k & 7);
      const bool isreal = !(t & 1);
      gB[p * 2048 + pp]        = isreal ? v : (f16)0.f;
      gB[p * 2048 + pp + 1024] = isreal ? (f16)0.f : v;
    }
  }
#pragma unroll
  for (int e = tid; e < 1024; e += BLOCK) {
    const int li = e >> 8, rp = (e >> 4) & 15, k = e & 15;
    const int base = 14 * li + 10;
    const float c0 = qc[base], c1 = qc[base+1], c2 = qc[base+2], c3 = qc[base+3];
    const float s0 = qs[base], s1 = qs[base+1], s2 = qs[base+2], s3 = qs[base+3];
    const int d = finv3(rp) ^ k;
    float mag = ((d & 1) ? s0 : c0) * ((d & 2) ? s1 : c1);
    mag *= ((d & 4) ? s2 : c2) * ((d & 8) ? s3 : c3);
    const int t = __popc(d) & 3;
    const f16 v = (f16)((t == 1 || t == 2) ? -mag : mag);
    const bool isreal = !(t & 1);
    const int pp = li * 512 + 16 * rp + k;
    gC[pp]       = isreal ? v : (f16)0.f;
    gC[pp + 256] = isreal ? (f16)0.f : v;
  }
}

// ---------------- per-wave fragment loaders (global, L1/L2-cached) ---------
struct FB { f16x8 br0, bi0, br1, bi1; };
struct FC { f16x4 ur0, ui0, ur1, ui1; };

__device__ __forceinline__ FB loadB(const f16* __restrict__ g, bool ctrl, int tid) {
  const int lane = tid & 63, wave = tid >> 6;
  const int q = lane >> 4, cc = lane & 15;
  int n0 = cc, n1 = cc | 16;
  if (ctrl && wave >= 4) { n0 ^= 31; n1 ^= 31; }   // ext-ctrl CNOT(4,5)
  FB f;
  f.br0 = *(const f16x8*)(g + 256 * q + 8 * n0);
  f.bi0 = *(const f16x8*)(g + 1024 + 256 * q + 8 * n0);
  f.br1 = *(const f16x8*)(g + 256 * q + 8 * n1);
  f.bi1 = *(const f16x8*)(g + 1024 + 256 * q + 8 * n1);
  return f;
}
__device__ __forceinline__ FC loadC(const f16* __restrict__ g, int tid) {
  const int lane = tid & 63;
  const int q = lane >> 4, cc = lane & 15;
  // both ext-ctrl(9,10) variants (ctrl = wire9 = half -> row^15)
  const int r0 = 16 * cc + 4 * q, r1 = 16 * (cc ^ 15) + 4 * q;
  FC f;
  f.ur0 = *(const f16x4*)(g + r0);
  f.ui0 = *(const f16x4*)(g + 256 + r0);
  f.ur1 = *(const f16x4*)(g + r1);
  f.ui1 = *(const f16x4*)(g + 256 + r1);
  return f;
}

// ---------------- exchange primitives (one 32 KB plane at a time) ----------
// NO __restrict__ on LDS pointers — stores and reads alias the same plane by
// design; barriers provide the ordering (R15 race lesson).
__device__ __forceinline__ void readFrag(const f16* stg, int tid, u32 st[16]) {
  const int lane = tid & 63, wave = tid >> 6;
  const int q = lane >> 4, cc = lane & 15;
#pragma unroll
  for (int i = 0; i < 4; ++i) {
    const int mt = wave * 4 + i;
    const u32x4 v = *(const u32x4*)(stg + mt * 512 + ((128 * q + 8 * cc) ^ swz(mt)));
    st[4 * i] = v[0]; st[4 * i + 1] = v[1]; st[4 * i + 2] = v[2]; st[4 * i + 3] = v[3];
  }
}
// passA-store of one plane: o[i*2+nt] <-> st[4i+2nt..+1]
__device__ __forceinline__ void storeA(f16* stg, int tid, const u32 st[16]) {
  const int lane = tid & 63, wave = tid >> 6;
  const int q = lane >> 4, cc = lane & 15;
#pragma unroll
  for (int i = 0; i < 4; ++i) {
    const int mt = wave * 4 + i;
#pragma unroll
    for (int nt = 0; nt < 2; ++nt) {
      const int n5 = nt * 16 + cc;
      const int pS = n5 * 512 +
          ((128 * (2 * (mt & 1) + (q >> 1)) + 8 * (mt >> 1) + 4 * (q & 1)) ^ swz(n5));
      u32x2 v; v[0] = st[4 * i + 2 * nt]; v[1] = st[4 * i + 2 * nt + 1];
      *(u32x2*)(stg + pS) = v;
    }
  }
}
// superBC-store of one plane: a[i][h] dword dj <-> st[4i+2h+dj]
__device__ __forceinline__ void storeBC(f16* stg, int tid, const u32 st[16]) {
  const int lane = tid & 63, wave = tid >> 6;
  const int q = lane >> 4, cc = lane & 15;
  const u32 selLo = (q & 2) ? 0x01000504u : 0x05040100u;
  const u32 selHi = (q & 2) ? 0x03020706u : 0x07060302u;
  const int ibase = 128 * (wave >> 1) + 4 * (wave & 1);
#pragma unroll
  for (int h = 0; h < 2; ++h) {
#pragma unroll
    for (int j = 0; j < 4; ++j) {
      const int pS = (8 * q + 2 * j + h) * 512 + ibase + 8 * (cc ^ (2 * j + h) ^ q);
      const int dj = j >> 1;
      const u32 sel = (j & 1) ? selHi : selLo;
      u32x2 v;
      v[0] = __builtin_amdgcn_perm(st[4 * 1 + 2 * h + dj], st[4 * 0 + 2 * h + dj], sel);
      v[1] = __builtin_amdgcn_perm(st[4 * 3 + 2 * h + dj], st[4 * 2 + 2 * h + dj], sel);
      *(u32x2*)(stg + pS) = v;
    }
  }
}
__device__ __forceinline__ void exchangeA(f16* stg, int tid, u32 stR[16], u32 stI[16]) {
  __syncthreads();                 // prior reads of staging done
  storeA(stg, tid, stR);
  __syncthreads();
  readFrag(stg, tid, stR);
  __syncthreads();                 // RE reads done before IM overwrite
  storeA(stg, tid, stI);
  __syncthreads();
  readFrag(stg, tid, stI);
}
__device__ __forceinline__ void exchangeBC(f16* stg, int tid, u32 stR[16], u32 stI[16]) {
  __syncthreads();
  storeBC(stg, tid, stR);
  __syncthreads();
  readFrag(stg, tid, stR);
  __syncthreads();
  storeBC(stg, tid, stI);
  __syncthreads();
  readFrag(stg, tid, stI);
}

// ---------------- compute phases (in-place on state slots) -----------------
// A-pass (wires 0-4, no ext ctrl): tile i read into temps, slots overwritten.
__device__ __forceinline__ void computeA(u32 stR[16], u32 stI[16], const FB& fb) {
#pragma unroll
  for (int i = 0; i < 4; ++i) {
    const f16x8 Ar = ld8(stR, i), Ai = ld8(stI, i);
    const f16x8 nAi = -Ai;
    {
      f32x4 aR = {0.f,0.f,0.f,0.f}, aI = {0.f,0.f,0.f,0.f};
      aR = mf(Ar, fb.br0, aR); aR = mf(nAi, fb.bi0, aR);
      aI = mf(Ar, fb.bi0, aI); aI = mf(Ai, fb.br0, aI);
      st4(stR, 4 * i + 0, cvt4(aR));
      st4(stI, 4 * i + 0, cvt4(aI));
    }
    {
      f32x4 aR = {0.f,0.f,0.f,0.f}, aI = {0.f,0.f,0.f,0.f};
      aR = mf(Ar, fb.br1, aR); aR = mf(nAi, fb.bi1, aR);
      aI = mf(Ar, fb.bi1, aI); aI = mf(Ai, fb.br1, aI);
      st4(stR, 4 * i + 2, cvt4(aR));
      st4(stI, 4 * i + 2, cvt4(aI));
    }
  }
}

// Fused B+C superpass (R11-verified algebra). FINAL: 6-acc readout
// (zacc = {z0b, z1b, z9b, zA, zB, pt}), expanded to zloc[14] by caller.
template<bool FINAL>
__device__ __forceinline__ void computeBC(u32 stR[16], u32 stI[16],
                                          const FB& fb, const FC& fc,
                                          float* zacc) {
#pragma unroll
  for (int i = 0; i < 4; ++i) {
    const f16x8 Ar = ld8(stR, i), Ai = ld8(stI, i);
    const f16x8 nAi = -Ai;
#pragma unroll
    for (int h = 0; h < 2; ++h) {
      const f16x8 br = h ? fb.br1 : fb.br0;
      const f16x8 bi = h ? fb.bi1 : fb.bi0;
      f32x4 aR = {0.f,0.f,0.f,0.f}, aI = {0.f,0.f,0.f,0.f};
      aR = mf(Ar, br, aR); aR = mf(nAi, bi, aR);
      aI = mf(Ar, bi, aI); aI = mf(Ai, br, aI);
      const f16x4 s1r = cvt4(aR), s1i = cvt4(aI);
      const f16x4 ur = h ? fc.ur1 : fc.ur0;
      const f16x4 ui = h ? fc.ui1 : fc.ui0;
      const f16x4 un = -ui;                           // transient -UCi
      f32x4 cR = {0.f,0.f,0.f,0.f}, cI = {0.f,0.f,0.f,0.f};
      cR = mf16(ur, s1r, cR); cR = mf16(un, s1i, cR);   // UCr*S1r - UCi*S1i
      cI = mf16(ui, s1r, cI); cI = mf16(ur, s1i, cI);   // UCi*S1r + UCr*S1i
      if constexpr (FINAL) {
        // element (wires): 0-1=i bits [+wrap], 2-4=wave bits, 5-8=cc bits,
        // 9=h, 10-11=j bits, 12-13=q bits; wrap handled by caller.
        const float p0 = cR[0]*cR[0] + cI[0]*cI[0];
        const float p1 = cR[1]*cR[1] + cI[1]*cI[1];
        const float p2 = cR[2]*cR[2] + cI[2]*cI[2];
        const float p3 = cR[3]*cR[3] + cI[3]*cI[3];
        const float ps = (p0 + p1) + (p2 + p3);
        zacc[3] += (p0 - p1) + (p2 - p3);          // Z10 (j bit0)
        zacc[4] += (p0 + p1) - (p2 + p3);          // Z11 (j bit1)
        zacc[0] += (i & 1) ? -ps : ps;             // z0b
        zacc[1] += (i & 2) ? -ps : ps;             // z1b
        zacc[2] += h ? -ps : ps;                   // z9b
        zacc[5] += ps;                             // pt
      } else {
        st4(stR, 4 * i + 2 * h, cvt4(cR));
        st4(stI, 4 * i + 2 * h, cvt4(cI));
      }
    }
  }
}

__global__ __launch_bounds__(BLOCK, 6) void qsim_kernel(
    const float* __restrict__ x, const float* __restrict__ qp,
    const float* __restrict__ fcw, const float* __restrict__ fcb,
    const f16* __restrict__ gB, const f16* __restrict__ gC,
    float* __restrict__ out) {
  extern __shared__ unsigned char smem[];
  f16* stg = (f16*)smem;                    // [16384] one-plane staging
  float* scratch = (float*)(stg + 16384);   // [128] init scratch / zpart
  float* qc = scratch + 128;                // [8]  (only 0..4 used)
  float* qs = qc + 8;                       // [8]
  float* xc = qs + 8;                       // [16] (only 0..13 used)
  float* xs = xc + 16;                      // [16]

  const int b = blockIdx.x;
  const int tid = threadIdx.x;

  // ---- angles ----
  if (tid < NQ) {
    float sv, cv; sincosf(0.5f * x[b * NQ + tid], &sv, &cv);
    xc[tid] = cv; xs[tid] = sv;
  } else if (tid >= 64 && tid < 64 + 5) {
    const int k = tid - 64;
    float sv, cv; sincosf(0.5f * qp[k], &sv, &cv);
    qc[k] = cv; qs[k] = sv;
  }
  __syncthreads();

  // ---- closed-form state at L1-B entry ----
  float* Flo  = scratch;            // [32]
  float* psi  = Flo + 32;           // [32]
  float* PsiR = psi + 32;           // [32]
  float* PsiI = PsiR + 32;          // [32]
  if (tid < 32) {
    float f = 1.f;
#pragma unroll
    for (int j = 0; j < 5; ++j) f *= ((tid >> j) & 1) ? xs[5 + j] : xc[5 + j];
    Flo[tid] = f;
  } else if (tid < 64) {
    const int k = tid - 32;
    float f = 1.f;
#pragma unroll
    for (int j = 0; j < 5; ++j) f *= ((k >> j) & 1) ? xs[j] : xc[j];
    psi[k] = f;
  }
  __syncthreads();
  if (tid < 32) {   // Psi = U_L1A * psi
    const float c0 = qc[0], c1 = qc[1], c2 = qc[2], c3 = qc[3], c4 = qc[4];
    const float s0 = qs[0], s1 = qs[1], s2 = qs[2], s3 = qs[3], s4 = qs[4];
    const int a = finv5(tid);
    float ar = 0.f, ai = 0.f;
    for (int k = 0; k < 32; ++k) {
      const int d = a ^ k;
      float mag = ((d & 1) ? s0 : c0) * ((d & 2) ? s1 : c1);
      mag *= ((d & 4) ? s2 : c2) * ((d & 8) ? s3 : c3);
      mag *= ((d & 16) ? s4 : c4);
      mag *= psi[k];
      const int t = __popc(d) & 3;
      if (t == 0) ar += mag; else if (t == 1) ai -= mag;
      else if (t == 2) ar -= mag; else ai += mag;
    }
    PsiR[tid] = ar; PsiI[tid] = ai;
  }
  __syncthreads();

  // ---- init exchange: write RE plane, read RE frags; same for IM ----
  u32 stR[16], stI[16];
  {
    float fhi = 1.f;
#pragma unroll
    for (int j = 0; j < 4; ++j) fhi *= ((tid >> j) & 1) ? xs[10 + j] : xc[10 + j];
    const float cr = fhi * PsiR[tid >> 4], ci = fhi * PsiI[tid >> 4];
    const int t = tid >> 4;
    const int sz = swz(t);
#pragma unroll
    for (int kb = 0; kb < 4; ++kb) {
      f16x8 hr;
#pragma unroll
      for (int j = 0; j < 8; ++j) hr[j] = (f16)(Flo[8 * kb + j] * cr);
      *(f16x8*)(stg + t * 512 + ((128 * kb + 8 * (tid & 15)) ^ sz)) = hr;
    }
    __syncthreads();
    readFrag(stg, tid, stR);
    __syncthreads();
#pragma unroll
    for (int kb = 0; kb < 4; ++kb) {
      f16x8 hi;
#pragma unroll
      for (int j = 0; j < 8; ++j) hi[j] = (f16)(Flo[8 * kb + j] * ci);
      *(f16x8*)(stg + t * 512 + ((128 * kb + 8 * (tid & 15)) ^ sz)) = hi;
    }
    __syncthreads();
    readFrag(stg, tid, stI);
  }

  // ---- 7 passes; state in register slots, staging exchange between ----
  // gB plane order {L1B, L2A, L2B, L3A, L3B, L4A, L4B}. fb/fc loaded just
  // before use (minimal live set).
  FB fb = loadB(gB, true, tid);                               // L1-B
  FC fc = loadC(gC, tid);
  computeBC<false>(stR, stI, fb, fc, nullptr);                // L1 B+C
  exchangeBC(stg, tid, stR, stI);

  fb = loadB(gB + 1 * 2048, false, tid);                      // L2-A
  computeA(stR, stI, fb);
  exchangeA(stg, tid, stR, stI);

  fb = loadB(gB + 2 * 2048, true, tid);                       // L2-B
  fc = loadC(gC + 1 * 512, tid);
  computeBC<false>(stR, stI, fb, fc, nullptr);
  exchangeBC(stg, tid, stR, stI);

  fb = loadB(gB + 3 * 2048, false, tid);                      // L3-A
  computeA(stR, stI, fb);
  exchangeA(stg, tid, stR, stI);

  fb = loadB(gB + 4 * 2048, true, tid);                       // L3-B
  fc = loadC(gC + 2 * 512, tid);
  computeBC<false>(stR, stI, fb, fc, nullptr);
  exchangeBC(stg, tid, stR, stI);

  fb = loadB(gB + 5 * 2048, false, tid);                      // L4-A
  computeA(stR, stI, fb);
  exchangeA(stg, tid, stR, stI);

  fb = loadB(gB + 6 * 2048, true, tid);                       // L4-B
  fc = loadC(gC + 3 * 512, tid);
  float zacc[6];
#pragma unroll
  for (int w = 0; w < 6; ++w) zacc[w] = 0.f;
  computeBC<true>(stR, stI, fb, fc, zacc);                    // L4 B+C + readout

  // expand 6 accumulators -> zloc[14] (state regs dead here)
  const int lane = tid & 63, wave = tid >> 6;
  const int q = lane >> 4, cc = lane & 15;
  float zloc[NQ];
  zloc[0]  = (q & 2) ? -zacc[0] : zacc[0];   // wrap CNOT(13,0) sign fold
  zloc[1]  = zacc[1];
  zloc[2]  = (wave & 1) ? -zacc[5] : zacc[5];
  zloc[3]  = (wave & 2) ? -zacc[5] : zacc[5];
  zloc[4]  = (wave & 4) ? -zacc[5] : zacc[5];
  zloc[5]  = (cc & 1) ? -zacc[5] : zacc[5];
  zloc[6]  = (cc & 2) ? -zacc[5] : zacc[5];
  zloc[7]  = (cc & 4) ? -zacc[5] : zacc[5];
  zloc[8]  = (cc & 8) ? -zacc[5] : zacc[5];
  zloc[9]  = zacc[2];
  zloc[10] = zacc[3];
  zloc[11] = zacc[4];
  zloc[12] = (q & 1) ? -zacc[5] : zacc[5];
  zloc[13] = (q & 2) ? -zacc[5] : zacc[5];
  __syncthreads();

  // ---- reduce + linear head (zpart aliases scratch) ----
  float* zpart = scratch;            // [8*14]
  float* zbuf  = zpart + 112;        // [14]
#pragma unroll
  for (int w = 0; w < NQ; ++w) {
#pragma unroll
    for (int off = 32; off > 0; off >>= 1)
      zloc[w] += __shfl_down(zloc[w], off, 64);
  }
  if (lane == 0) {
#pragma unroll
    for (int w = 0; w < NQ; ++w) zpart[wave * NQ + w] = zloc[w];
  }
  __syncthreads();
  if (tid < NQ) {
    float a = 0.f;
#pragma unroll
    for (int v = 0; v < 8; ++v) a += zpart[v * NQ + tid];
    zbuf[tid] = a;
  }
  __syncthreads();
  if (tid < NCLASSES) {
    float acc = fcb[tid];
#pragma unroll
    for (int w = 0; w < NQ; ++w) acc = fmaf(zbuf[w], fcw[tid * NQ + w], acc);
    out[b * NCLASSES + tid] = acc;
  }
}

extern "C" void kernel_launch(void* const* d_in, const int* in_sizes, int n_in,
                              void* d_out, int out_size, void* d_ws, size_t ws_size,
                              hipStream_t stream) {
  const float* x   = (const float*)d_in[0];
  const float* qp  = (const float*)d_in[1];
  const float* fcw = (const float*)d_in[2];
  const float* fcb = (const float*)d_in[3];
  float* out = (float*)d_out;
  const int B = in_sizes[0] / NQ;

  f16* gB = (f16*)d_ws;              // 7 * 2048 f16 = 28672 B
  f16* gC = gB + 7 * 2048;           // 4 * 512 f16  =  4096 B (total 32 KB)

  qsim_build<<<1, BLOCK, 0, stream>>>(qp, gB, gC);

  const size_t shmem = (size_t)16384 * sizeof(f16)
                     + (size_t)(128 + 8 + 8 + 16 + 16) * sizeof(float);  // 33472 B
  (void)hipFuncSetAttribute((const void*)qsim_kernel,
                            hipFuncAttributeMaxDynamicSharedMemorySize, (int)shmem);
  qsim_kernel<<<B, BLOCK, shmem, stream>>>(x, qp, fcw, fcb, gB, gC, out);
}

// Round 9
// 145.606 us; speedup vs baseline: 1.6936x; 1.3618x over previous
//
#include <hip/hip_runtime.h>
#include <hip/hip_fp16.h>
#include <math.h>

// 14-qubit batched statevector sim, MFMA engine. R19 = R18 (CORRECT: RNE fix
// verified, absmax 0.0046 — but still scratch-demoted: peak ~90 naive / ~80
// actual vs (512,6) cap 80) with the 24 pass-long frag VGPRs moved to LDS:
//   - B-plane (4 KB, double-buffered Bb0/Bb1) + C-plane (1 KB) in LDS,
//     copied global->LDS ONE PASS AHEAD inside pass bodies (R12-style fold;
//     ordering covered by the exchange's 4 barriers). BC passes read Bb0 and
//     copy the next A-plane into Bb1; A passes read Bb1 and copy the next
//     B-plane into Bb0 + next C-plane into Cc.
//   - Frags read PER-TILE from LDS so they are transient, not pass-long.
//     LICM/CSE defeated via opaque-zero address offsets
//     (asm volatile("" : "+v"(oz)) per tile) — compiler cannot prove the
//     tiles' loads identical, so no hoist back into pass-long registers.
//   - Peak VGPR ~= 32 state + ~44 overlapping transients ~= 72-76 < cap 80
//     -> 3 blocks/CU (24 waves). LDS 42.7 KB (3 blocks fit 128 KB).
//   - Everything else byte-identical to R18: slot-union state stR/stI[16],
//     RNE cvt4, 4-barrier single-plane exchange, 6-acc FINAL readout, no
//     __restrict__ on LDS pointers (R15 race lesson).
//
// Layouts kept from R7/R8/R11/R13 (verified):
//   staging (per plane): phys = t*512 + ((128*(k>>3) + 8*mlow + (k&7)) ^ swz(t))
//   B planes octet-major: re at 256*(k>>3)+8*n+(k&7), im at +1024.
//   C planes (A-frag order): UCr at 16*r+k, UCi at +256.
//   Superpass store: pS = (8q+2j+h)*512 + 128*(wave>>1)+4*(wave&1)
//                         + 8*(cc ^ (2j+h) ^ q), wrap CNOT(13,0) in v_perm sel.
// LDS: 32768 staging + 8192 Bb dbuf + 1024 Cc + 512 scratch + 192 angles
//      = 42688 B.

#define NQ 14
#define NLAYERS 4
#define NCLASSES 10
#define BLOCK 512

typedef _Float16 f16;
typedef _Float16 f16x4 __attribute__((ext_vector_type(4)));
typedef _Float16 f16x8 __attribute__((ext_vector_type(8)));
typedef float f32x4 __attribute__((ext_vector_type(4)));
typedef unsigned int u32;
typedef u32 u32x2 __attribute__((ext_vector_type(2)));
typedef u32 u32x4 __attribute__((ext_vector_type(4)));

__device__ __forceinline__ f32x4 mf(f16x8 a, f16x8 b, f32x4 c) {
  return __builtin_amdgcn_mfma_f32_16x16x32_f16(a, b, c, 0, 0, 0);
}
__device__ __forceinline__ f32x4 mf16(f16x4 a, f16x4 b, f32x4 c) {
  return __builtin_amdgcn_mfma_f32_16x16x16f16(a, b, c, 0, 0, 0);
}
__device__ __forceinline__ int swz(int t) { return ((t ^ (t >> 3)) & 7) << 3; }

// f32x4 -> f16x4, ROUND-TO-NEAREST-EVEN (R18 fix, verified absmax 0.0046).
__device__ __forceinline__ f16x4 cvt4(f32x4 v) {
  f16x4 r;
  r[0] = (f16)v[0]; r[1] = (f16)v[1]; r[2] = (f16)v[2]; r[3] = (f16)v[3];
  return r;
}

// state-slot helpers (all indices compile-time constant in unrolled loops)
__device__ __forceinline__ f16x8 ld8(const u32 st[16], int i) {
  u32x4 v = { st[4 * i], st[4 * i + 1], st[4 * i + 2], st[4 * i + 3] };
  return __builtin_bit_cast(f16x8, v);
}
__device__ __forceinline__ void st4(u32 st[16], int idx, f16x4 v) {
  const u32x2 d = __builtin_bit_cast(u32x2, v);
  st[idx] = d[0]; st[idx + 1] = d[1];
}

__device__ __forceinline__ int finv5(int n) {
  n ^= ((n >> 3) & 1) << 4;
  n ^= ((n >> 2) & 1) << 3;
  n ^= ((n >> 1) & 1) << 2;
  n ^= (n & 1) << 1;
  return n;
}
__device__ __forceinline__ int finv3(int n) {
  n ^= ((n >> 2) & 1) << 3;
  n ^= ((n >> 1) & 1) << 2;
  n ^= (n & 1) << 1;
  return n;
}

// ---------------- pre-kernel: build all U planes once into workspace -------
// gB: 7 planes x 2048 f16 (re [0,1024), im [1024,2048)), pass order
//     {L1B, L2A, L2B, L3A, L3B, L4A, L4B}.
// gC: 4 layers x 512 f16 (UCr at 16r+k, UCi at +256), base = 14*l + 10.
__global__ void qsim_build(const float* __restrict__ qp,
                           f16* __restrict__ gB, f16* __restrict__ gC) {
  __shared__ float qc[NLAYERS * NQ], qs[NLAYERS * NQ];
  const int tid = threadIdx.x;
  if (tid < NLAYERS * NQ) {
    float sv, cv; sincosf(0.5f * qp[tid], &sv, &cv);
    qc[tid] = cv; qs[tid] = sv;
  }
  __syncthreads();
#pragma unroll
  for (int p = 0; p < 7; ++p) {
    const int l = (p + 1) >> 1;
    const int base = 14 * l + ((p & 1) ? 0 : 5);
    const float c0 = qc[base], c1 = qc[base+1], c2 = qc[base+2], c3 = qc[base+3], c4 = qc[base+4];
    const float s0 = qs[base], s1 = qs[base+1], s2 = qs[base+2], s3 = qs[base+3], s4 = qs[base+4];
#pragma unroll
    for (int e = tid; e < 1024; e += BLOCK) {
      const int n = e >> 5, k = e & 31;
      const int d = finv5(n) ^ k;
      float mag = ((d & 1) ? s0 : c0) * ((d & 2) ? s1 : c1);
      mag *= ((d & 4) ? s2 : c2) * ((d & 8) ? s3 : c3);
      mag *= ((d & 16) ? s4 : c4);
      const int t = __popc(d) & 3;
      const f16 v = (f16)((t == 1 || t == 2) ? -mag : mag);
      const int pp = 256 * (k >> 3) + 8 * n + (k & 7);
      const bool isreal = !(t & 1);
      gB[p * 2048 + pp]        = isreal ? v : (f16)0.f;
      gB[p * 2048 + pp + 1024] = isreal ? (f16)0.f : v;
    }
  }
#pragma unroll
  for (int e = tid; e < 1024; e += BLOCK) {
    const int li = e >> 8, rp = (e >> 4) & 15, k = e & 15;
    const int base = 14 * li + 10;
    const float c0 = qc[base], c1 = qc[base+1], c2 = qc[base+2], c3 = qc[base+3];
    const float s0 = qs[base], s1 = qs[base+1], s2 = qs[base+2], s3 = qs[base+3];
    const int d = finv3(rp) ^ k;
    float mag = ((d & 1) ? s0 : c0) * ((d & 2) ? s1 : c1);
    mag *= ((d & 4) ? s2 : c2) * ((d & 8) ? s3 : c3);
    const int t = __popc(d) & 3;
    const f16 v = (f16)((t == 1 || t == 2) ? -mag : mag);
    const bool isreal = !(t & 1);
    const int pp = li * 512 + 16 * rp + k;
    gC[pp]       = isreal ? v : (f16)0.f;
    gC[pp + 256] = isreal ? (f16)0.f : v;
  }
}

// ---------------- plane copies (global -> LDS), folded into pass bodies ----
__device__ __forceinline__ void copyB(f16* dst, const f16* __restrict__ src, int tid) {
#pragma unroll
  for (int k = tid; k < 1024; k += BLOCK)
    ((u32*)dst)[k] = ((const u32*)src)[k];
}
__device__ __forceinline__ void copyC(f16* dst, const f16* __restrict__ src, int tid) {
  if (tid < 256) ((u32*)dst)[tid] = ((const u32*)src)[tid];
}

// ---------------- exchange primitives (one 32 KB plane at a time) ----------
// NO __restrict__ on LDS pointers — stores and reads alias the same plane by
// design; barriers provide the ordering (R15 race lesson).
__device__ __forceinline__ void readFrag(const f16* stg, int tid, u32 st[16]) {
  const int lane = tid & 63, wave = tid >> 6;
  const int q = lane >> 4, cc = lane & 15;
#pragma unroll
  for (int i = 0; i < 4; ++i) {
    const int mt = wave * 4 + i;
    const u32x4 v = *(const u32x4*)(stg + mt * 512 + ((128 * q + 8 * cc) ^ swz(mt)));
    st[4 * i] = v[0]; st[4 * i + 1] = v[1]; st[4 * i + 2] = v[2]; st[4 * i + 3] = v[3];
  }
}
// passA-store of one plane: o[i*2+nt] <-> st[4i+2nt..+1]
__device__ __forceinline__ void storeA(f16* stg, int tid, const u32 st[16]) {
  const int lane = tid & 63, wave = tid >> 6;
  const int q = lane >> 4, cc = lane & 15;
#pragma unroll
  for (int i = 0; i < 4; ++i) {
    const int mt = wave * 4 + i;
#pragma unroll
    for (int nt = 0; nt < 2; ++nt) {
      const int n5 = nt * 16 + cc;
      const int pS = n5 * 512 +
          ((128 * (2 * (mt & 1) + (q >> 1)) + 8 * (mt >> 1) + 4 * (q & 1)) ^ swz(n5));
      u32x2 v; v[0] = st[4 * i + 2 * nt]; v[1] = st[4 * i + 2 * nt + 1];
      *(u32x2*)(stg + pS) = v;
    }
  }
}
// superBC-store of one plane: a[i][h] dword dj <-> st[4i+2h+dj]
__device__ __forceinline__ void storeBC(f16* stg, int tid, const u32 st[16]) {
  const int lane = tid & 63, wave = tid >> 6;
  const int q = lane >> 4, cc = lane & 15;
  const u32 selLo = (q & 2) ? 0x01000504u : 0x05040100u;
  const u32 selHi = (q & 2) ? 0x03020706u : 0x07060302u;
  const int ibase = 128 * (wave >> 1) + 4 * (wave & 1);
#pragma unroll
  for (int h = 0; h < 2; ++h) {
#pragma unroll
    for (int j = 0; j < 4; ++j) {
      const int pS = (8 * q + 2 * j + h) * 512 + ibase + 8 * (cc ^ (2 * j + h) ^ q);
      const int dj = j >> 1;
      const u32 sel = (j & 1) ? selHi : selLo;
      u32x2 v;
      v[0] = __builtin_amdgcn_perm(st[4 * 1 + 2 * h + dj], st[4 * 0 + 2 * h + dj], sel);
      v[1] = __builtin_amdgcn_perm(st[4 * 3 + 2 * h + dj], st[4 * 2 + 2 * h + dj], sel);
      *(u32x2*)(stg + pS) = v;
    }
  }
}
__device__ __forceinline__ void exchangeA(f16* stg, int tid, u32 stR[16], u32 stI[16]) {
  __syncthreads();                 // prior reads of staging done
  storeA(stg, tid, stR);
  __syncthreads();
  readFrag(stg, tid, stR);
  __syncthreads();                 // RE reads done before IM overwrite
  storeA(stg, tid, stI);
  __syncthreads();
  readFrag(stg, tid, stI);
}
__device__ __forceinline__ void exchangeBC(f16* stg, int tid, u32 stR[16], u32 stI[16]) {
  __syncthreads();
  storeBC(stg, tid, stR);
  __syncthreads();
  readFrag(stg, tid, stR);
  __syncthreads();
  storeBC(stg, tid, stI);
  __syncthreads();
  readFrag(stg, tid, stI);
}

// ---------------- compute phases (in-place on state slots) -----------------
// Frags read PER-TILE from LDS; opaque zero defeats LICM/CSE so the frag
// values stay iteration-local (transient) instead of pass-long.
// A-pass (wires 0-4, no ext ctrl). Copies next B-plane -> BbW, next C -> CcW.
__device__ __forceinline__ void computeA(u32 stR[16], u32 stI[16],
                                         const f16* Bb,
                                         const f16* __restrict__ gNB, f16* BbW,
                                         const f16* __restrict__ gNC, f16* CcW,
                                         int tid) {
  copyB(BbW, gNB, tid);
  copyC(CcW, gNC, tid);
  const int lane = tid & 63;
  const int q = lane >> 4, cc = lane & 15;
  const int n0 = cc, n1 = cc | 16;
#pragma unroll
  for (int i = 0; i < 4; ++i) {
    int oz = 0; asm volatile("" : "+v"(oz));
    const f16* Bz = Bb + oz;
    const f16x8 br0 = *(const f16x8*)(Bz + 256 * q + 8 * n0);
    const f16x8 bi0 = *(const f16x8*)(Bz + 1024 + 256 * q + 8 * n0);
    const f16x8 br1 = *(const f16x8*)(Bz + 256 * q + 8 * n1);
    const f16x8 bi1 = *(const f16x8*)(Bz + 1024 + 256 * q + 8 * n1);
    const f16x8 Ar = ld8(stR, i), Ai = ld8(stI, i);
    const f16x8 nAi = -Ai;
    {
      f32x4 aR = {0.f,0.f,0.f,0.f}, aI = {0.f,0.f,0.f,0.f};
      aR = mf(Ar, br0, aR); aR = mf(nAi, bi0, aR);
      aI = mf(Ar, bi0, aI); aI = mf(Ai, br0, aI);
      st4(stR, 4 * i + 0, cvt4(aR));
      st4(stI, 4 * i + 0, cvt4(aI));
    }
    {
      f32x4 aR = {0.f,0.f,0.f,0.f}, aI = {0.f,0.f,0.f,0.f};
      aR = mf(Ar, br1, aR); aR = mf(nAi, bi1, aR);
      aI = mf(Ar, bi1, aI); aI = mf(Ai, br1, aI);
      st4(stR, 4 * i + 2, cvt4(aR));
      st4(stI, 4 * i + 2, cvt4(aI));
    }
  }
}

// Fused B+C superpass (R11-verified algebra; ext-ctrl CNOT(4,5) wave flip).
// Non-final copies next A-plane -> BbW. FINAL: 6-acc readout.
template<bool FINAL>
__device__ __forceinline__ void computeBC(u32 stR[16], u32 stI[16],
                                          const f16* Bb, const f16* Cc,
                                          const f16* __restrict__ gNB, f16* BbW,
                                          int tid, float* zacc) {
  if constexpr (!FINAL) copyB(BbW, gNB, tid);
  const int lane = tid & 63, wave = tid >> 6;
  const int q = lane >> 4, cc = lane & 15;
  int n0 = cc, n1 = cc | 16;
  if (wave >= 4) { n0 ^= 31; n1 ^= 31; }   // ext-ctrl CNOT(4,5)
  const int r0 = 16 * cc + 4 * q, r1 = 16 * (cc ^ 15) + 4 * q;
#pragma unroll
  for (int i = 0; i < 4; ++i) {
    int oz = 0; asm volatile("" : "+v"(oz));
    const f16* Bz = Bb + oz;
    const f16* Cz = Cc + oz;
    const f16x8 br0 = *(const f16x8*)(Bz + 256 * q + 8 * n0);
    const f16x8 bi0 = *(const f16x8*)(Bz + 1024 + 256 * q + 8 * n0);
    const f16x8 br1 = *(const f16x8*)(Bz + 256 * q + 8 * n1);
    const f16x8 bi1 = *(const f16x8*)(Bz + 1024 + 256 * q + 8 * n1);
    const f16x4 ur0 = *(const f16x4*)(Cz + r0);
    const f16x4 ui0 = *(const f16x4*)(Cz + 256 + r0);
    const f16x4 ur1 = *(const f16x4*)(Cz + r1);
    const f16x4 ui1 = *(const f16x4*)(Cz + 256 + r1);
    const f16x8 Ar = ld8(stR, i), Ai = ld8(stI, i);
    const f16x8 nAi = -Ai;
#pragma unroll
    for (int h = 0; h < 2; ++h) {
      const f16x8 br = h ? br1 : br0;
      const f16x8 bi = h ? bi1 : bi0;
      f32x4 aR = {0.f,0.f,0.f,0.f}, aI = {0.f,0.f,0.f,0.f};
      aR = mf(Ar, br, aR); aR = mf(nAi, bi, aR);
      aI = mf(Ar, bi, aI); aI = mf(Ai, br, aI);
      const f16x4 s1r = cvt4(aR), s1i = cvt4(aI);
      const f16x4 ur = h ? ur1 : ur0;
      const f16x4 ui = h ? ui1 : ui0;
      const f16x4 un = -ui;                           // transient -UCi
      f32x4 cR = {0.f,0.f,0.f,0.f}, cI = {0.f,0.f,0.f,0.f};
      cR = mf16(ur, s1r, cR); cR = mf16(un, s1i, cR);   // UCr*S1r - UCi*S1i
      cI = mf16(ui, s1r, cI); cI = mf16(ur, s1i, cI);   // UCi*S1r + UCr*S1i
      if constexpr (FINAL) {
        // element (wires): 0-1=i bits [+wrap], 2-4=wave bits, 5-8=cc bits,
        // 9=h, 10-11=j bits, 12-13=q bits; wrap handled by caller.
        const float p0 = cR[0]*cR[0] + cI[0]*cI[0];
        const float p1 = cR[1]*cR[1] + cI[1]*cI[1];
        const float p2 = cR[2]*cR[2] + cI[2]*cI[2];
        const float p3 = cR[3]*cR[3] + cI[3]*cI[3];
        const float ps = (p0 + p1) + (p2 + p3);
        zacc[3] += (p0 - p1) + (p2 - p3);          // Z10 (j bit0)
        zacc[4] += (p0 + p1) - (p2 + p3);          // Z11 (j bit1)
        zacc[0] += (i & 1) ? -ps : ps;             // z0b
        zacc[1] += (i & 2) ? -ps : ps;             // z1b
        zacc[2] += h ? -ps : ps;                   // z9b
        zacc[5] += ps;                             // pt
      } else {
        st4(stR, 4 * i + 2 * h, cvt4(cR));
        st4(stI, 4 * i + 2 * h, cvt4(cI));
      }
    }
  }
}

__global__ __launch_bounds__(BLOCK, 6) void qsim_kernel(
    const float* __restrict__ x, const float* __restrict__ qp,
    const float* __restrict__ fcw, const float* __restrict__ fcb,
    const f16* __restrict__ gB, const f16* __restrict__ gC,
    float* __restrict__ out) {
  extern __shared__ unsigned char smem[];
  f16* stg = (f16*)smem;                    // [16384] one-plane staging
  f16* Bb0 = stg + 16384;                   // [2048] B-plane buffer 0
  f16* Bb1 = Bb0 + 2048;                    // [2048] B-plane buffer 1
  f16* CcL = Bb1 + 2048;                    // [512]  C-plane buffer
  float* scratch = (float*)(CcL + 512);     // [128] init scratch / zpart
  float* qc = scratch + 128;                // [8]  (only 0..4 used)
  float* qs = qc + 8;                       // [8]
  float* xc = qs + 8;                       // [16] (only 0..13 used)
  float* xs = xc + 16;                      // [16]

  const int b = blockIdx.x;
  const int tid = threadIdx.x;

  // ---- initial plane copies (readers are after several init barriers) ----
  copyB(Bb0, gB, tid);                      // L1-B plane
  copyC(CcL, gC, tid);                      // C(L1)

  // ---- angles ----
  if (tid < NQ) {
    float sv, cv; sincosf(0.5f * x[b * NQ + tid], &sv, &cv);
    xc[tid] = cv; xs[tid] = sv;
  } else if (tid >= 64 && tid < 64 + 5) {
    const int k = tid - 64;
    float sv, cv; sincosf(0.5f * qp[k], &sv, &cv);
    qc[k] = cv; qs[k] = sv;
  }
  __syncthreads();

  // ---- closed-form state at L1-B entry ----
  float* Flo  = scratch;            // [32]
  float* psi  = Flo + 32;           // [32]
  float* PsiR = psi + 32;           // [32]
  float* PsiI = PsiR + 32;          // [32]
  if (tid < 32) {
    float f = 1.f;
#pragma unroll
    for (int j = 0; j < 5; ++j) f *= ((tid >> j) & 1) ? xs[5 + j] : xc[5 + j];
    Flo[tid] = f;
  } else if (tid < 64) {
    const int k = tid - 32;
    float f = 1.f;
#pragma unroll
    for (int j = 0; j < 5; ++j) f *= ((k >> j) & 1) ? xs[j] : xc[j];
    psi[k] = f;
  }
  __syncthreads();
  if (tid < 32) {   // Psi = U_L1A * psi
    const float c0 = qc[0], c1 = qc[1], c2 = qc[2], c3 = qc[3], c4 = qc[4];
    const float s0 = qs[0], s1 = qs[1], s2 = qs[2], s3 = qs[3], s4 = qs[4];
    const int a = finv5(tid);
    float ar = 0.f, ai = 0.f;
    for (int k = 0; k < 32; ++k) {
      const int d = a ^ k;
      float mag = ((d & 1) ? s0 : c0) * ((d & 2) ? s1 : c1);
      mag *= ((d & 4) ? s2 : c2) * ((d & 8) ? s3 : c3);
      mag *= ((d & 16) ? s4 : c4);
      mag *= psi[k];
      const int t = __popc(d) & 3;
      if (t == 0) ar += mag; else if (t == 1) ai -= mag;
      else if (t == 2) ar -= mag; else ai += mag;
    }
    PsiR[tid] = ar; PsiI[tid] = ai;
  }
  __syncthreads();

  // ---- init exchange: write RE plane, read RE frags; same for IM ----
  u32 stR[16], stI[16];
  {
    float fhi = 1.f;
#pragma unroll
    for (int j = 0; j < 4; ++j) fhi *= ((tid >> j) & 1) ? xs[10 + j] : xc[10 + j];
    const float cr = fhi * PsiR[tid >> 4], ci = fhi * PsiI[tid >> 4];
    const int t = tid >> 4;
    const int sz = swz(t);
#pragma unroll
    for (int kb = 0; kb < 4; ++kb) {
      f16x8 hr;
#pragma unroll
      for (int j = 0; j < 8; ++j) hr[j] = (f16)(Flo[8 * kb + j] * cr);
      *(f16x8*)(stg + t * 512 + ((128 * kb + 8 * (tid & 15)) ^ sz)) = hr;
    }
    __syncthreads();
    readFrag(stg, tid, stR);
    __syncthreads();
#pragma unroll
    for (int kb = 0; kb < 4; ++kb) {
      f16x8 hi;
#pragma unroll
      for (int j = 0; j < 8; ++j) hi[j] = (f16)(Flo[8 * kb + j] * ci);
      *(f16x8*)(stg + t * 512 + ((128 * kb + 8 * (tid & 15)) ^ sz)) = hi;
    }
    __syncthreads();
    readFrag(stg, tid, stI);
  }

  // ---- 7 passes; state in register slots, frags via LDS plane buffers ----
  // gB plane order {L1B, L2A, L2B, L3A, L3B, L4A, L4B}. BC passes read Bb0
  // (copy next A-plane into Bb1); A passes read Bb1 (copy next B into Bb0,
  // next C into CcL). Copy ordering guaranteed by the exchange barriers.
  computeBC<false>(stR, stI, Bb0, CcL, gB + 1 * 2048, Bb1, tid, nullptr); // L1 B+C
  exchangeBC(stg, tid, stR, stI);

  computeA(stR, stI, Bb1, gB + 2 * 2048, Bb0, gC + 1 * 512, CcL, tid);   // L2 A
  exchangeA(stg, tid, stR, stI);

  computeBC<false>(stR, stI, Bb0, CcL, gB + 3 * 2048, Bb1, tid, nullptr); // L2 B+C
  exchangeBC(stg, tid, stR, stI);

  computeA(stR, stI, Bb1, gB + 4 * 2048, Bb0, gC + 2 * 512, CcL, tid);   // L3 A
  exchangeA(stg, tid, stR, stI);

  computeBC<false>(stR, stI, Bb0, CcL, gB + 5 * 2048, Bb1, tid, nullptr); // L3 B+C
  exchangeBC(stg, tid, stR, stI);

  computeA(stR, stI, Bb1, gB + 6 * 2048, Bb0, gC + 3 * 512, CcL, tid);   // L4 A
  exchangeA(stg, tid, stR, stI);

  float zacc[6];
#pragma unroll
  for (int w = 0; w < 6; ++w) zacc[w] = 0.f;
  computeBC<true>(stR, stI, Bb0, CcL, nullptr, nullptr, tid, zacc);      // L4 B+C

  // expand 6 accumulators -> zloc[14] (state regs dead here)
  const int lane = tid & 63, wave = tid >> 6;
  const int q = lane >> 4, cc = lane & 15;
  float zloc[NQ];
  zloc[0]  = (q & 2) ? -zacc[0] : zacc[0];   // wrap CNOT(13,0) sign fold
  zloc[1]  = zacc[1];
  zloc[2]  = (wave & 1) ? -zacc[5] : zacc[5];
  zloc[3]  = (wave & 2) ? -zacc[5] : zacc[5];
  zloc[4]  = (wave & 4) ? -zacc[5] : zacc[5];
  zloc[5]  = (cc & 1) ? -zacc[5] : zacc[5];
  zloc[6]  = (cc & 2) ? -zacc[5] : zacc[5];
  zloc[7]  = (cc & 4) ? -zacc[5] : zacc[5];
  zloc[8]  = (cc & 8) ? -zacc[5] : zacc[5];
  zloc[9]  = zacc[2];
  zloc[10] = zacc[3];
  zloc[11] = zacc[4];
  zloc[12] = (q & 1) ? -zacc[5] : zacc[5];
  zloc[13] = (q & 2) ? -zacc[5] : zacc[5];
  __syncthreads();

  // ---- reduce + linear head (zpart aliases scratch) ----
  float* zpart = scratch;            // [8*14]
  float* zbuf  = zpart + 112;        // [14]
#pragma unroll
  for (int w = 0; w < NQ; ++w) {
#pragma unroll
    for (int off = 32; off > 0; off >>= 1)
      zloc[w] += __shfl_down(zloc[w], off, 64);
  }
  if (lane == 0) {
#pragma unroll
    for (int w = 0; w < NQ; ++w) zpart[wave * NQ + w] = zloc[w];
  }
  __syncthreads();
  if (tid < NQ) {
    float a = 0.f;
#pragma unroll
    for (int v = 0; v < 8; ++v) a += zpart[v * NQ + tid];
    zbuf[tid] = a;
  }
  __syncthreads();
  if (tid < NCLASSES) {
    float acc = fcb[tid];
#pragma unroll
    for (int w = 0; w < NQ; ++w) acc = fmaf(zbuf[w], fcw[tid * NQ + w], acc);
    out[b * NCLASSES + tid] = acc;
  }
}

extern "C" void kernel_launch(void* const* d_in, const int* in_sizes, int n_in,
                              void* d_out, int out_size, void* d_ws, size_t ws_size,
                              hipStream_t stream) {
  const float* x   = (const float*)d_in[0];
  const float* qp  = (const float*)d_in[1];
  const float* fcw = (const float*)d_in[2];
  const float* fcb = (const float*)d_in[3];
  float* out = (float*)d_out;
  const int B = in_sizes[0] / NQ;

  f16* gB = (f16*)d_ws;              // 7 * 2048 f16 = 28672 B
  f16* gC = gB + 7 * 2048;           // 4 * 512 f16  =  4096 B (total 32 KB)

  qsim_build<<<1, BLOCK, 0, stream>>>(qp, gB, gC);

  const size_t shmem = (size_t)(16384 + 2048 + 2048 + 512) * sizeof(f16)
                     + (size_t)(128 + 8 + 8 + 16 + 16) * sizeof(float);  // 42688 B
  (void)hipFuncSetAttribute((const void*)qsim_kernel,
                            hipFuncAttributeMaxDynamicSharedMemorySize, (int)shmem);
  qsim_kernel<<<B, BLOCK, shmem, stream>>>(x, qp, fcw, fcb, gB, gC, out);
}

// Round 10
// 119.399 us; speedup vs baseline: 2.0654x; 1.2195x over previous
//
#include <hip/hip_runtime.h>
#include <hip/hip_fp16.h>
#include <math.h>

// 14-qubit batched statevector sim, MFMA engine. R20 = exact revert to R13,
// the verified best (kernel 68.2 us, bench 119.6 us, VGPR 64, no spill).
// R14-R19 post-mortems: the register-resident-state/occupancy path needs
// ~100 VGPR structurally (32 state + 16 B-frags + temps + f32 accs) vs the
// 80-cap required for 3 blocks/CU; three de-pressurization attempts (no
// prefetch, slot-union, LDS frags) all still scratch-demoted, and block
// granularity (8 waves) makes intermediate caps unusable. Occupancy path
// closed; R13 structure restored verbatim:
//   1) U-plane builds in a 1-block pre-kernel (q_params-only, shared by all
//      1024 blocks) -> d_ws; main kernel loads MFMA B/C frags from global
//      (L1/L2-cached), prefetched ONE PASS AHEAD post-internal-barrier.
//   2) Two-plane LDS state (reP/imP), 2 barriers/pass, 7 passes
//      (L1 B+C fused; per layer A + fused B+C; final pass fused readout).
//
// Layouts (R7/R8/R11-verified):
//   F32: phys = t*512 + ((128*(k>>3) + 8*mlow + (k&7)) ^ swz(t))
//   B-planes octet-major: re at 256*(k>>3)+8*n+(k&7), im at +1024.
//   C-planes (A-frag order): UCr at 16*r+k, UCi at +256.
//   Superpass store: pS = (8q+2j+h)*512 + 128*(wave>>1)+4*(wave&1)
//                         + 8*(cc ^ (2j+h) ^ q), wrap CNOT(13,0) in v_perm sel.
// LDS: 65536 state + 512 scratch + 192 angles = 66240 B (2 blocks/CU).

#define NQ 14
#define NLAYERS 4
#define NCLASSES 10
#define BLOCK 512

typedef _Float16 f16;
typedef _Float16 f16x2 __attribute__((ext_vector_type(2)));
typedef _Float16 f16x4 __attribute__((ext_vector_type(4)));
typedef _Float16 f16x8 __attribute__((ext_vector_type(8)));
typedef float f32x4 __attribute__((ext_vector_type(4)));
typedef unsigned int u32;
typedef u32 u32x2 __attribute__((ext_vector_type(2)));

__device__ __forceinline__ f32x4 mf(f16x8 a, f16x8 b, f32x4 c) {
  return __builtin_amdgcn_mfma_f32_16x16x32_f16(a, b, c, 0, 0, 0);
}
__device__ __forceinline__ f32x4 mf16(f16x4 a, f16x4 b, f32x4 c) {
  return __builtin_amdgcn_mfma_f32_16x16x16f16(a, b, c, 0, 0, 0);
}
__device__ __forceinline__ int swz(int t) { return ((t ^ (t >> 3)) & 7) << 3; }

// packed f32x4 -> f16x4 (2x v_cvt_pkrtz_f16_f32)
__device__ __forceinline__ f16x4 cvt4(f32x4 v) {
  u32x2 r;
  r[0] = __builtin_bit_cast(u32, __builtin_amdgcn_cvt_pkrtz(v[0], v[1]));
  r[1] = __builtin_bit_cast(u32, __builtin_amdgcn_cvt_pkrtz(v[2], v[3]));
  return __builtin_bit_cast(f16x4, r);
}
__device__ __forceinline__ u32 dwof(f16x4 v, int k) {
  return __builtin_bit_cast(u32x2, v)[k];
}

__device__ __forceinline__ int finv5(int n) {
  n ^= ((n >> 3) & 1) << 4;
  n ^= ((n >> 2) & 1) << 3;
  n ^= ((n >> 1) & 1) << 2;
  n ^= (n & 1) << 1;
  return n;
}
__device__ __forceinline__ int finv3(int n) {
  n ^= ((n >> 2) & 1) << 3;
  n ^= ((n >> 1) & 1) << 2;
  n ^= (n & 1) << 1;
  return n;
}

// ---------------- pre-kernel: build all U planes once into workspace -------
// gB: 7 planes x 2048 f16 (re [0,1024), im [1024,2048)), pass order
//     {L1B, L2A, L2B, L3A, L3B, L4A, L4B}; plane p: layer l=(p+1)/2,
//     base = 14*l + (p odd ? 0 : 5).
// gC: 4 layers x 512 f16 (UCr at 16r+k, UCi at +256), base = 14*l + 10.
__global__ void qsim_build(const float* __restrict__ qp,
                           f16* __restrict__ gB, f16* __restrict__ gC) {
  __shared__ float qc[NLAYERS * NQ], qs[NLAYERS * NQ];
  const int tid = threadIdx.x;
  if (tid < NLAYERS * NQ) {
    float sv, cv; sincosf(0.5f * qp[tid], &sv, &cv);
    qc[tid] = cv; qs[tid] = sv;
  }
  __syncthreads();
#pragma unroll
  for (int p = 0; p < 7; ++p) {
    const int l = (p + 1) >> 1;
    const int base = 14 * l + ((p & 1) ? 0 : 5);
    const float c0 = qc[base], c1 = qc[base+1], c2 = qc[base+2], c3 = qc[base+3], c4 = qc[base+4];
    const float s0 = qs[base], s1 = qs[base+1], s2 = qs[base+2], s3 = qs[base+3], s4 = qs[base+4];
#pragma unroll
    for (int e = tid; e < 1024; e += BLOCK) {
      const int n = e >> 5, k = e & 31;
      const int d = finv5(n) ^ k;
      float mag = ((d & 1) ? s0 : c0) * ((d & 2) ? s1 : c1);
      mag *= ((d & 4) ? s2 : c2) * ((d & 8) ? s3 : c3);
      mag *= ((d & 16) ? s4 : c4);
      const int t = __popc(d) & 3;
      const f16 v = (f16)((t == 1 || t == 2) ? -mag : mag);
      const int pp = 256 * (k >> 3) + 8 * n + (k & 7);
      const bool isreal = !(t & 1);
      gB[p * 2048 + pp]        = isreal ? v : (f16)0.f;
      gB[p * 2048 + pp + 1024] = isreal ? (f16)0.f : v;
    }
  }
#pragma unroll
  for (int e = tid; e < 1024; e += BLOCK) {
    const int li = e >> 8, rp = (e >> 4) & 15, k = e & 15;
    const int base = 14 * li + 10;
    const float c0 = qc[base], c1 = qc[base+1], c2 = qc[base+2], c3 = qc[base+3];
    const float s0 = qs[base], s1 = qs[base+1], s2 = qs[base+2], s3 = qs[base+3];
    const int d = finv3(rp) ^ k;
    float mag = ((d & 1) ? s0 : c0) * ((d & 2) ? s1 : c1);
    mag *= ((d & 4) ? s2 : c2) * ((d & 8) ? s3 : c3);
    const int t = __popc(d) & 3;
    const f16 v = (f16)((t == 1 || t == 2) ? -mag : mag);
    const bool isreal = !(t & 1);
    const int pp = li * 512 + 16 * rp + k;
    gC[pp]       = isreal ? v : (f16)0.f;
    gC[pp + 256] = isreal ? (f16)0.f : v;
  }
}

// ---------------- per-wave fragment loaders (global, L1/L2-cached) ---------
struct FB { f16x8 br0, bi0, br1, bi1; };
struct FC { f16x4 ur0, ui0, ur1, ui1; };

__device__ __forceinline__ FB loadB(const f16* __restrict__ g, bool ctrl, int tid) {
  const int lane = tid & 63, wave = tid >> 6;
  const int q = lane >> 4, cc = lane & 15;
  int n0 = cc, n1 = cc | 16;
  if (ctrl && wave >= 4) { n0 ^= 31; n1 ^= 31; }   // ext-ctrl CNOT(4,5)
  FB f;
  f.br0 = *(const f16x8*)(g + 256 * q + 8 * n0);
  f.bi0 = *(const f16x8*)(g + 1024 + 256 * q + 8 * n0);
  f.br1 = *(const f16x8*)(g + 256 * q + 8 * n1);
  f.bi1 = *(const f16x8*)(g + 1024 + 256 * q + 8 * n1);
  return f;
}
__device__ __forceinline__ FC loadC(const f16* __restrict__ g, int tid) {
  const int lane = tid & 63;
  const int q = lane >> 4, cc = lane & 15;
  // both ext-ctrl(9,10) variants (ctrl = wire9 = half -> row^15)
  const int r0 = 16 * cc + 4 * q, r1 = 16 * (cc ^ 15) + 4 * q;
  FC f;
  f.ur0 = *(const f16x4*)(g + r0);
  f.ui0 = *(const f16x4*)(g + 256 + r0);
  f.ur1 = *(const f16x4*)(g + r1);
  f.ui1 = *(const f16x4*)(g + 256 + r1);
  return f;
}

// A-pass (wires 0-4, no ext ctrl). Frags arrive pre-loaded in registers;
// prefetches next superBC's B-frags + C-frags right after the internal sync.
__device__ __forceinline__ void passA(f16* __restrict__ reP, f16* __restrict__ imP,
                                      const FB fb,
                                      const f16* __restrict__ gNB,
                                      const f16* __restrict__ gNC,
                                      FB* __restrict__ nextB,
                                      FC* __restrict__ nextC, int tid) {
  const int lane = tid & 63, wave = tid >> 6;
  const int q = lane >> 4, cc = lane & 15;
  f16x8 Ar[4], Ai[4];
#pragma unroll
  for (int i = 0; i < 4; ++i) {
    const int mt = wave * 4 + i;
    const int pA = mt * 512 + ((128 * q + 8 * cc) ^ swz(mt));
    Ar[i] = *(const f16x8*)(reP + pA);
    Ai[i] = *(const f16x8*)(imP + pA);
  }
  __syncthreads();   // all state reads done before in-place permuted writes
  *nextB = loadB(gNB, true, tid);   // drains at trailing barrier
  *nextC = loadC(gNC, tid);
  f16x4 outR[8], outI[8];
#pragma unroll
  for (int i = 0; i < 4; ++i) {
    const f16x8 nAi = -Ai[i];
    {
      f32x4 aR = {0.f,0.f,0.f,0.f}, aI = {0.f,0.f,0.f,0.f};
      aR = mf(Ar[i], fb.br0, aR); aR = mf(nAi, fb.bi0, aR);
      aI = mf(Ar[i], fb.bi0, aI); aI = mf(Ai[i], fb.br0, aI);
      outR[i * 2 + 0] = cvt4(aR);
      outI[i * 2 + 0] = cvt4(aI);
    }
    {
      f32x4 aR = {0.f,0.f,0.f,0.f}, aI = {0.f,0.f,0.f,0.f};
      aR = mf(Ar[i], fb.br1, aR); aR = mf(nAi, fb.bi1, aR);
      aI = mf(Ar[i], fb.bi1, aI); aI = mf(Ai[i], fb.br1, aI);
      outR[i * 2 + 1] = cvt4(aR);
      outI[i * 2 + 1] = cvt4(aI);
    }
  }
#pragma unroll
  for (int i = 0; i < 4; ++i) {
    const int mt = wave * 4 + i;
#pragma unroll
    for (int nt = 0; nt < 2; ++nt) {
      const int n5 = nt * 16 + cc;
      const int pS = n5 * 512 +
          ((128 * (2 * (mt & 1) + (q >> 1)) + 8 * (mt >> 1) + 4 * (q & 1)) ^ swz(n5));
      *(f16x4*)(reP + pS) = outR[i * 2 + nt];
      *(f16x4*)(imP + pS) = outI[i * 2 + nt];
    }
  }
}

// Fused B+C superpass (R11-verified algebra). Frags pre-loaded; non-final
// prefetches next passA's B-frags. FINAL: no stores -> no internal sync,
// fused readout from the C accumulators.
template<bool FINAL>
__device__ __forceinline__ void superBC(f16* __restrict__ reP, f16* __restrict__ imP,
                                        const FB fb, const FC fc,
                                        const f16* __restrict__ gNB,
                                        FB* __restrict__ nextB,
                                        int tid, float* __restrict__ zloc) {
  const int lane = tid & 63, wave = tid >> 6;
  const int q = lane >> 4, cc = lane & 15;
  f16x8 Ar[4], Ai[4];
#pragma unroll
  for (int i = 0; i < 4; ++i) {
    const int mt = wave * 4 + i;
    const int pA = mt * 512 + ((128 * q + 8 * cc) ^ swz(mt));
    Ar[i] = *(const f16x8*)(reP + pA);
    Ai[i] = *(const f16x8*)(imP + pA);
  }
  if constexpr (!FINAL) {
    __syncthreads();               // reads done before in-place writes
    *nextB = loadB(gNB, false, tid);   // drains at trailing barrier
  }
  const f16x4 ucn0 = -fc.ui0, ucn1 = -fc.ui1;   // -UCi planes in-register

  f16x4 accR[4][2], accI[4][2];   // [i][half] (non-final)
  float z0b = 0.f, z1b = 0.f, z9b = 0.f, zA = 0.f, zB = 0.f, pt = 0.f;
#pragma unroll
  for (int i = 0; i < 4; ++i) {
    const f16x8 nAi = -Ai[i];
#pragma unroll
    for (int h = 0; h < 2; ++h) {
      const f16x8 br = h ? fb.br1 : fb.br0;
      const f16x8 bi = h ? fb.bi1 : fb.bi0;
      f32x4 aR = {0.f,0.f,0.f,0.f}, aI = {0.f,0.f,0.f,0.f};
      aR = mf(Ar[i], br, aR); aR = mf(nAi, bi, aR);
      aI = mf(Ar[i], bi, aI); aI = mf(Ai[i], br, aI);
      const f16x4 s1r = cvt4(aR), s1i = cvt4(aI);
      const f16x4 ur = h ? fc.ur1 : fc.ur0;
      const f16x4 ui = h ? fc.ui1 : fc.ui0;
      const f16x4 un = h ? ucn1 : ucn0;
      f32x4 cR = {0.f,0.f,0.f,0.f}, cI = {0.f,0.f,0.f,0.f};
      cR = mf16(ur, s1r, cR); cR = mf16(un, s1i, cR);   // UCr*S1r - UCi*S1i
      cI = mf16(ui, s1r, cI); cI = mf16(ur, s1i, cI);   // UCi*S1r + UCr*S1i
      if constexpr (FINAL) {
        // element (wires): 0-1=i bits [+wrap], 2-4=wave bits, 5-8=cc bits,
        // 9=h, 10-11=j bits, 12-13=q bits; wrap: wire0 ^= (q>>1).
        const float p0 = cR[0]*cR[0] + cI[0]*cI[0];
        const float p1 = cR[1]*cR[1] + cI[1]*cI[1];
        const float p2 = cR[2]*cR[2] + cI[2]*cI[2];
        const float p3 = cR[3]*cR[3] + cI[3]*cI[3];
        const float ps = (p0 + p1) + (p2 + p3);
        zA += (p0 - p1) + (p2 - p3);          // Z10 (j bit0)
        zB += (p0 + p1) - (p2 + p3);          // Z11 (j bit1)
        z0b += (i & 1) ? -ps : ps;
        z1b += (i & 2) ? -ps : ps;
        z9b += h ? -ps : ps;
        pt  += ps;
      } else {
        accR[i][h] = cvt4(cR);
        accI[i][h] = cvt4(cI);
      }
    }
  }
  if constexpr (FINAL) {
    zloc[0]  += (q & 2) ? -z0b : z0b;   // wrap CNOT(13,0) sign fold
    zloc[1]  += z1b;
    zloc[2]  += (wave & 1) ? -pt : pt;
    zloc[3]  += (wave & 2) ? -pt : pt;
    zloc[4]  += (wave & 4) ? -pt : pt;
    zloc[5]  += (cc & 1) ? -pt : pt;
    zloc[6]  += (cc & 2) ? -pt : pt;
    zloc[7]  += (cc & 4) ? -pt : pt;
    zloc[8]  += (cc & 8) ? -pt : pt;
    zloc[9]  += z9b;
    zloc[10] += zA;
    zloc[11] += zB;
    zloc[12] += (q & 1) ? -pt : pt;
    zloc[13] += (q & 2) ? -pt : pt;
  } else {
    // run (j,h) = f16x4 over i=0..3 (wires 0-1); wrap CNOT(13,0): lanes with
    // q>=2 swap i0<->i1, i2<->i3 (folded into the v_perm selector).
    const u32 selLo = (q & 2) ? 0x01000504u : 0x05040100u;
    const u32 selHi = (q & 2) ? 0x03020706u : 0x07060302u;
    const int ibase = 128 * (wave >> 1) + 4 * (wave & 1);
#pragma unroll
    for (int h = 0; h < 2; ++h) {
#pragma unroll
      for (int j = 0; j < 4; ++j) {
        const int pS = (8 * q + 2 * j + h) * 512 + ibase +
                       8 * (cc ^ (2 * j + h) ^ q);
        const int dj = j >> 1;
        const u32 sel = (j & 1) ? selHi : selLo;
        u32x2 vr, vi;
        vr[0] = __builtin_amdgcn_perm(dwof(accR[1][h], dj), dwof(accR[0][h], dj), sel);
        vr[1] = __builtin_amdgcn_perm(dwof(accR[3][h], dj), dwof(accR[2][h], dj), sel);
        vi[0] = __builtin_amdgcn_perm(dwof(accI[1][h], dj), dwof(accI[0][h], dj), sel);
        vi[1] = __builtin_amdgcn_perm(dwof(accI[3][h], dj), dwof(accI[2][h], dj), sel);
        *(u32x2*)(reP + pS) = vr;
        *(u32x2*)(imP + pS) = vi;
      }
    }
  }
}

__global__ __launch_bounds__(BLOCK, 4) void qsim_kernel(
    const float* __restrict__ x, const float* __restrict__ qp,
    const float* __restrict__ fcw, const float* __restrict__ fcb,
    const f16* __restrict__ gB, const f16* __restrict__ gC,
    float* __restrict__ out) {
  extern __shared__ unsigned char smem[];
  f16* reP = (f16*)smem;                    // [16384]
  f16* imP = reP + 16384;                   // [16384]
  float* scratch = (float*)(imP + 16384);   // [128] init scratch / zpart
  float* qc = scratch + 128;                // [8]  (only 0..4 used)
  float* qs = qc + 8;                       // [8]
  float* xc = qs + 8;                       // [16] (only 0..13 used)
  float* xs = xc + 16;                      // [16]

  const int b = blockIdx.x;
  const int tid = threadIdx.x;

  // L1-B / L1-C frags: issue global loads immediately (drain at init barriers)
  FB fb = loadB(gB, true, tid);
  FC fc = loadC(gC, tid);

  // ---- angles ----
  if (tid < NQ) {
    float sv, cv; sincosf(0.5f * x[b * NQ + tid], &sv, &cv);
    xc[tid] = cv; xs[tid] = sv;
  } else if (tid >= 64 && tid < 64 + 5) {
    const int k = tid - 64;
    float sv, cv; sincosf(0.5f * qp[k], &sv, &cv);
    qc[k] = cv; qs[k] = sv;
  }
  __syncthreads();

  // ---- closed-form state at L1-B entry ----
  float* Flo  = scratch;            // [32]
  float* psi  = Flo + 32;           // [32]
  float* PsiR = psi + 32;           // [32]
  float* PsiI = PsiR + 32;          // [32]
  if (tid < 32) {
    float f = 1.f;
#pragma unroll
    for (int j = 0; j < 5; ++j) f *= ((tid >> j) & 1) ? xs[5 + j] : xc[5 + j];
    Flo[tid] = f;
  } else if (tid < 64) {
    const int k = tid - 32;
    float f = 1.f;
#pragma unroll
    for (int j = 0; j < 5; ++j) f *= ((k >> j) & 1) ? xs[j] : xc[j];
    psi[k] = f;
  }
  __syncthreads();
  if (tid < 32) {   // Psi = U_L1A * psi
    const float c0 = qc[0], c1 = qc[1], c2 = qc[2], c3 = qc[3], c4 = qc[4];
    const float s0 = qs[0], s1 = qs[1], s2 = qs[2], s3 = qs[3], s4 = qs[4];
    const int a = finv5(tid);
    float ar = 0.f, ai = 0.f;
    for (int k = 0; k < 32; ++k) {
      const int d = a ^ k;
      float mag = ((d & 1) ? s0 : c0) * ((d & 2) ? s1 : c1);
      mag *= ((d & 4) ? s2 : c2) * ((d & 8) ? s3 : c3);
      mag *= ((d & 16) ? s4 : c4);
      mag *= psi[k];
      const int t = __popc(d) & 3;
      if (t == 0) ar += mag; else if (t == 1) ai -= mag;
      else if (t == 2) ar -= mag; else ai += mag;
    }
    PsiR[tid] = ar; PsiI[tid] = ai;
  }
  __syncthreads();
  {  // state at L1-B entry: amp(e = tid*32 + k) -> F32 layout
    float fhi = 1.f;
#pragma unroll
    for (int j = 0; j < 4; ++j) fhi *= ((tid >> j) & 1) ? xs[10 + j] : xc[10 + j];
    const float cr = fhi * PsiR[tid >> 4], ci = fhi * PsiI[tid >> 4];
    const int t = tid >> 4;
    const int sz = swz(t);
#pragma unroll
    for (int kb = 0; kb < 4; ++kb) {
      f16x8 hr, hi;
#pragma unroll
      for (int j = 0; j < 8; ++j) {
        const float F = Flo[8 * kb + j];
        hr[j] = (f16)(F * cr);
        hi[j] = (f16)(F * ci);
      }
      const int pb = t * 512 + ((128 * kb + 8 * (tid & 15)) ^ sz);
      *(f16x8*)(reP + pb) = hr;
      *(f16x8*)(imP + pb) = hi;
    }
  }
  __syncthreads();

  // ---- 7 GEMM passes; B/C frags stream from global, prefetched 1 ahead ----
  // gB plane order {L1B, L2A, L2B, L3A, L3B, L4A, L4B}: layer l (1..3) has
  // A-plane 2l-1, B-plane 2l.
  FB fbN; FC fcN;
  superBC<false>(reP, imP, fb, fc, gB + 1 * 2048, &fbN, tid, nullptr);
  __syncthreads();
#pragma unroll
  for (int l = 1; l < NLAYERS; ++l) {
    passA(reP, imP, fbN, gB + (2 * l) * 2048, gC + l * 512, &fb, &fc, tid);
    __syncthreads();
    if (l < NLAYERS - 1) {
      superBC<false>(reP, imP, fb, fc, gB + (2 * l + 1) * 2048, &fbN, tid, nullptr);
      __syncthreads();
    }
  }

  float zloc[NQ];
#pragma unroll
  for (int w = 0; w < NQ; ++w) zloc[w] = 0.f;
  superBC<true>(reP, imP, fb, fc, nullptr, nullptr, tid, zloc);  // L4 + readout
  __syncthreads();

  // ---- reduce + linear head (zpart aliases scratch) ----
  float* zpart = scratch;            // [8*14]
  float* zbuf  = zpart + 112;        // [14]
#pragma unroll
  for (int w = 0; w < NQ; ++w) {
#pragma unroll
    for (int off = 32; off > 0; off >>= 1)
      zloc[w] += __shfl_down(zloc[w], off, 64);
  }
  const int wave = tid >> 6, lane = tid & 63;
  if (lane == 0) {
#pragma unroll
    for (int w = 0; w < NQ; ++w) zpart[wave * NQ + w] = zloc[w];
  }
  __syncthreads();
  if (tid < NQ) {
    float a = 0.f;
#pragma unroll
    for (int v = 0; v < 8; ++v) a += zpart[v * NQ + tid];
    zbuf[tid] = a;
  }
  __syncthreads();
  if (tid < NCLASSES) {
    float acc = fcb[tid];
#pragma unroll
    for (int w = 0; w < NQ; ++w) acc = fmaf(zbuf[w], fcw[tid * NQ + w], acc);
    out[b * NCLASSES + tid] = acc;
  }
}

extern "C" void kernel_launch(void* const* d_in, const int* in_sizes, int n_in,
                              void* d_out, int out_size, void* d_ws, size_t ws_size,
                              hipStream_t stream) {
  const float* x   = (const float*)d_in[0];
  const float* qp  = (const float*)d_in[1];
  const float* fcw = (const float*)d_in[2];
  const float* fcb = (const float*)d_in[3];
  float* out = (float*)d_out;
  const int B = in_sizes[0] / NQ;

  f16* gB = (f16*)d_ws;              // 7 * 2048 f16 = 28672 B
  f16* gC = gB + 7 * 2048;           // 4 * 512 f16  =  4096 B (total 32 KB)

  qsim_build<<<1, BLOCK, 0, stream>>>(qp, gB, gC);

  const size_t shmem = (size_t)(2 * 16384) * sizeof(f16)
                     + (size_t)(128 + 8 + 8 + 16 + 16) * sizeof(float);  // 66240 B
  (void)hipFuncSetAttribute((const void*)qsim_kernel,
                            hipFuncAttributeMaxDynamicSharedMemorySize, (int)shmem);
  qsim_kernel<<<B, BLOCK, shmem, stream>>>(x, qp, fcw, fcb, gB, gC, out);
}